// Round 7
// baseline (601.814 us; speedup 1.0000x reference)
//
#include <hip/hip_runtime.h>
#include <hip/hip_bf16.h>

typedef unsigned short u16;
typedef unsigned int u32;
typedef __bf16 bf16x8_t __attribute__((ext_vector_type(8)));
typedef float f32x4_t __attribute__((ext_vector_type(4)));

#define BK 64

__device__ __forceinline__ float b2f(u16 v) {
  return __uint_as_float(((u32)v) << 16);
}
__device__ __forceinline__ u16 f2b(float f) {
  __hip_bfloat16 h = __float2bfloat16(f);
  return *reinterpret_cast<u16*>(&h);
}
__device__ __forceinline__ float blo(u32 u) { return __uint_as_float(u << 16); }
__device__ __forceinline__ float bhi(u32 u) { return __uint_as_float(u & 0xffff0000u); }

__device__ __forceinline__ void async_lds16(const u16* g, u16* l) {
  __builtin_amdgcn_global_load_lds(
      (__attribute__((address_space(1))) void*)g,
      (__attribute__((address_space(3))) void*)l, 16, 0, 0);
}

__device__ __forceinline__ void expand8(const float* __restrict__ w,
                                        u16* __restrict__ dst, int I,
                                        int kshift, int gid) {
  const int n = gid >> kshift;
  const int kc = (gid & ((1 << kshift) - 1)) * 8;
  const int K = 8 << kshift;
  const float* wp = w + (size_t)((n >> 3) * I + (kc >> 3)) * 8;
  float4 w0 = *(const float4*)wp;
  float4 w1 = *(const float4*)(wp + 4);
  float w8[8] = {w0.x, w0.y, w0.z, w0.w, w1.x, w1.y, w1.z, w1.w};
  u16 t[8];
  const int r = (n - kc) & 7;
#pragma unroll
  for (int j = 0; j < 8; ++j) t[j] = f2b(w8[(r - j) & 7]);
  *(uint4*)(dst + (size_t)n * K + kc) = *(const uint4*)t;
}

// fp32 -> bf16, 8 elements per thread, vectorized.
__device__ __forceinline__ void cvt8(const float* __restrict__ src,
                                     u16* __restrict__ dst, int gid) {
  const float* p = src + (size_t)gid * 8;
  float4 a = *(const float4*)p;
  float4 b = *(const float4*)(p + 4);
  u16 t[8] = {f2b(a.x), f2b(a.y), f2b(a.z), f2b(a.w),
              f2b(b.x), f2b(b.y), f2b(b.z), f2b(b.w)};
  *(uint4*)(dst + (size_t)gid * 8) = *(const uint4*)t;
}

// blocks [0,8192): circulant weight expansion (4 weights x 2048 blocks).
// blocks [8192, 8192+3*cblocks): q/k/v fp32->bf16 conversion.
__global__ __launch_bounds__(256) void expand_all(
    const float* __restrict__ w_q, const float* __restrict__ w_k,
    const float* __restrict__ w_v, const float* __restrict__ w_fc,
    const float* __restrict__ q, const float* __restrict__ k,
    const float* __restrict__ v, u16* __restrict__ Wq, u16* __restrict__ Wk,
    u16* __restrict__ Wv, u16* __restrict__ Wfc, u16* __restrict__ qb,
    u16* __restrict__ kb, u16* __restrict__ vb, int cblocks) {
  const int e = blockIdx.x;
  if (e < 8192) {
    const int plane = e >> 11;
    const int gid = (e & 2047) * 256 + threadIdx.x;
    if (plane == 0) expand8(w_q, Wq, 128, 7, gid);
    else if (plane == 1) expand8(w_k, Wk, 128, 7, gid);
    else if (plane == 2) expand8(w_v, Wv, 128, 7, gid);
    else expand8(w_fc, Wfc, 512, 9, gid);
  } else {
    const int ce = e - 8192;
    const int plane = ce / cblocks;
    const int gid = (ce - plane * cblocks) * 256 + threadIdx.x;
    if (plane == 0) cvt8(q, qb, gid);
    else if (plane == 1) cvt8(k, kb, gid);
    else cvt8(v, vb, gid);
  }
}

// ---------------------------------------------------------------------------
// 8-phase 256x256 QKV GEMM (R6, passed; equal-best qkv variant). BK=64,
// 512 thr = 8 waves (2M x 4N). vmcnt(4) only at P4/P8.
// ---------------------------------------------------------------------------
__global__ __launch_bounds__(512, 2) void gemm_qkv8p(
    const u16* __restrict__ X0, const u16* __restrict__ X1,
    const u16* __restrict__ X2, const u16* __restrict__ W0,
    const u16* __restrict__ W1, const u16* __restrict__ W2,
    const float* __restrict__ b0v, const float* __restrict__ b1v,
    const float* __restrict__ b2v, u16* __restrict__ Y0, u16* __restrict__ Y1,
    u16* __restrict__ Y2, int M, int N, int K) {
  __shared__ __align__(16) u16 lds[65536];  // 128 KB
  const int z = blockIdx.y;
  const u16* X = (z == 0) ? X0 : (z == 1) ? X1 : X2;
  const u16* W = (z == 0) ? W0 : (z == 1) ? W1 : W2;
  const float* bias = (z == 0) ? b0v : (z == 1) ? b1v : b2v;
  u16* Y = (z == 0) ? Y0 : (z == 1) ? Y1 : Y2;

  const int tid = threadIdx.x;
  const int bid = blockIdx.x;
  const int grid_m = M >> 8, grid_n = N >> 8;
  const int nb = grid_m * grid_n;
  int pid = (bid & 7) * (nb >> 3) + (bid >> 3);  // XCD-chunked swizzle
  const int nig = 8 * grid_n;
  const int group_id = pid / nig;
  const int first_m = group_id * 8;
  const int gsz = min(8, grid_m - first_m);
  const int mt = first_m + (pid % gsz);
  const int ntile = (pid % nig) / gsz;
  const int m0 = mt << 8, n0 = ntile << 8;

  const int lane = tid & 63, wave = tid >> 6;
  const int wg = wave >> 2;   // m-group: rows wg*128..+127
  const int wq = wave & 3;    // n-group: cols wq*64..+63
  const int l16 = lane & 15, quad = lane >> 4;
  const int lswz = l16 & 7;

  const u16* gA = X + (size_t)m0 * K;
  const u16* gB = W + (size_t)n0 * K;
  const int srow = tid >> 3;                  // 0..63
  const int skbg = (tid & 7) ^ (srow & 7);    // pre-swizzled source k-slot

  f32x4_t acc[8][4] = {};
  const int KT = K >> 6;      // BK=64 tiles (16 for K=1024)
  const int niter = KT >> 1;  // 2 tiles per iteration

  auto stg = [&](int kt, int h, bool isB) {
    u16* l = lds + (isB ? 32768 : 0) + ((kt & 1) * 2 + h) * 8192 + tid * 8;
    const u16* g = (isB ? gB : gA) + (size_t)(h * 128 + srow) * K + kt * 64 +
                   skbg * 8;
    async_lds16(g, l);
    async_lds16(g + (size_t)64 * K, l + 4096);
  };
  auto ldA = [&](int kt, int mh, bf16x8_t (&a)[8]) {
    const u16* base = lds + ((kt & 1) * 2 + wg) * 8192 + (mh * 64 + l16) * 64;
#pragma unroll
    for (int mi = 0; mi < 4; ++mi)
#pragma unroll
      for (int ks = 0; ks < 2; ++ks)
        a[mi * 2 + ks] = *(const bf16x8_t*)(base + mi * 1024 +
                                            (((ks * 4 + quad) ^ lswz) * 8));
  };
  auto ldB = [&](int kt, int nh, bf16x8_t (&b)[4]) {
    const u16* base = lds + 32768 + ((kt & 1) * 2 + (wq >> 1)) * 8192 +
                      ((wq & 1) * 64 + nh * 32 + l16) * 64;
#pragma unroll
    for (int ni = 0; ni < 2; ++ni)
#pragma unroll
      for (int ks = 0; ks < 2; ++ks)
        b[ni * 2 + ks] = *(const bf16x8_t*)(base + ni * 1024 +
                                            (((ks * 4 + quad) ^ lswz) * 8));
  };
  auto mm = [&](int mh, int nh, bf16x8_t (&a)[8], bf16x8_t (&b)[4]) {
    __builtin_amdgcn_s_setprio(1);
#pragma unroll
    for (int mi = 0; mi < 4; ++mi)
#pragma unroll
      for (int ni = 0; ni < 2; ++ni)
#pragma unroll
        for (int ks = 0; ks < 2; ++ks)
          acc[mh * 4 + mi][nh * 2 + ni] = __builtin_amdgcn_mfma_f32_16x16x32_bf16(
              a[mi * 2 + ks], b[ni * 2 + ks], acc[mh * 4 + mi][nh * 2 + ni], 0,
              0, 0);
    __builtin_amdgcn_s_setprio(0);
  };
  auto bar = [] { __builtin_amdgcn_s_barrier(); };
  auto lgkm0 = [] {
    asm volatile("s_waitcnt lgkmcnt(0)" ::: "memory");
    __builtin_amdgcn_sched_barrier(0);
  };
  auto sched = [] { __builtin_amdgcn_sched_barrier(0); };

  bf16x8_t a0[8], a1[8], b0[4], b1[4];

  stg(0, 0, false); sched();
  stg(0, 0, true);  sched();
  stg(0, 1, false); sched();
  stg(0, 1, true);  sched();
  stg(1, 0, true);  sched();
  stg(1, 0, false); sched();
  asm volatile("s_waitcnt vmcnt(4)" ::: "memory");
  bar();
  sched();

  for (int it = 0; it < niter; ++it) {
    const int t = it * 2;
    const bool more = (t + 2 < KT);
    ldA(t, 0, a0); ldB(t, 0, b0);
    stg(t + 1, 1, false);
    sched(); bar(); lgkm0();
    mm(0, 0, a0, b0);
    bar();
    ldB(t, 1, b1);
    stg(t + 1, 1, true);
    sched(); bar(); lgkm0();
    mm(0, 1, a0, b1);
    bar();
    ldA(t, 1, a1);
    if (more) stg(t + 2, 0, true);
    sched(); bar(); lgkm0();
    mm(1, 1, a1, b1);
    bar();
    if (more) stg(t + 2, 0, false);
    sched();
    if (more) asm volatile("s_waitcnt vmcnt(4)" ::: "memory");
    else      asm volatile("s_waitcnt vmcnt(0)" ::: "memory");
    bar(); lgkm0();
    mm(1, 0, a1, b0);
    bar();
    ldA(t + 1, 0, a0); ldB(t + 1, 0, b0);
    if (more) stg(t + 2, 1, false);
    sched(); bar(); lgkm0();
    mm(0, 0, a0, b0);
    bar();
    ldB(t + 1, 1, b1);
    if (more) stg(t + 2, 1, true);
    sched(); bar(); lgkm0();
    mm(0, 1, a0, b1);
    bar();
    ldA(t + 1, 1, a1);
    if (more) stg(t + 3, 0, true);
    sched(); bar(); lgkm0();
    mm(1, 1, a1, b1);
    bar();
    if (more) {
      stg(t + 3, 0, false);
      sched();
      asm volatile("s_waitcnt vmcnt(4)" ::: "memory");
      bar(); lgkm0();
      mm(1, 0, a1, b0);
      bar();
    } else {
      lgkm0();
      mm(1, 0, a1, b0);
    }
  }

#pragma unroll
  for (int ni = 0; ni < 4; ++ni) {
    const int col = n0 + wq * 64 + ni * 16 + l16;
    const float bv = bias[col >> 3];
#pragma unroll
    for (int mi = 0; mi < 8; ++mi) {
#pragma unroll
      for (int r = 0; r < 4; ++r) {
        const int rw = m0 + wg * 128 + mi * 16 + quad * 4 + r;
        Y[(size_t)rw * N + col] = f2b(acc[mi][ni][r] + bv);
      }
    }
  }
}

// ---------------------------------------------------------------------------
// fc GEMM: R0/R1-proven 2-barrier structure. TILE_M=128, TILE_N=TN, BK=64,
// 256 thr, 32 KB LDS -> ~3 blocks/CU. TN=128 when grid allows >=2 blk/CU.
// ---------------------------------------------------------------------------
template <int TN, bool HAS_RES, bool OUT_F32>
__device__ __forceinline__ void gemm_core(
    const u16* __restrict__ Xb, const u16* __restrict__ W,
    const float* __restrict__ bias, const float* __restrict__ res,
    void* __restrict__ Yv, int M, int N, int K, int bid) {
  __shared__ __align__(16) u16 As[128 * BK];
  __shared__ __align__(16) u16 Bs[TN * BK];
  const int tid = threadIdx.x;

  const int grid_m = M >> 7, grid_n = N / TN;
  const int nb = grid_m * grid_n;
  int pid = (bid & 7) * (nb >> 3) + (bid >> 3);
  const int nig = 8 * grid_n;
  const int group_id = pid / nig;
  const int first_m = group_id * 8;
  const int gsz = min(8, grid_m - first_m);
  const int mt = first_m + (pid % gsz);
  const int nt = (pid % nig) / gsz;
  const int m0 = mt << 7, n0 = nt * TN;

  const int lane = tid & 63;
  const int wave = tid >> 6;
  const int wm = (wave >> 1) * 64;
  const int wn = (wave & 1) * (TN / 2);
  const int l16 = lane & 15;
  const int quad = lane >> 4;
  constexpr int NJ = TN >> 5;

  f32x4_t acc[4][NJ] = {};

  const int row0 = tid >> 3;
  const int kgl = ((tid & 7) ^ (row0 & 7)) * 8;

  for (int k0 = 0; k0 < K; k0 += BK) {
#pragma unroll
    for (int it = 0; it < TN / 32; ++it)
      async_lds16(W + (size_t)(n0 + row0 + it * 32) * K + (k0 + kgl),
                  &Bs[(tid + it * 256) * 8]);
#pragma unroll
    for (int it = 0; it < 4; ++it)
      async_lds16(Xb + (size_t)(m0 + row0 + it * 32) * K + (k0 + kgl),
                  &As[(tid + it * 256) * 8]);
    __syncthreads();
#pragma unroll
    for (int half = 0; half < 2; ++half) {
      bf16x8_t af[4], bfr[NJ];
#pragma unroll
      for (int i = 0; i < 4; ++i)
        af[i] = *(const bf16x8_t*)&As[(wm + i * 16 + l16) * BK +
                                      (((quad + half * 4) ^ (l16 & 7)) * 8)];
#pragma unroll
      for (int j = 0; j < NJ; ++j)
        bfr[j] = *(const bf16x8_t*)&Bs[(wn + j * 16 + l16) * BK +
                                       (((quad + half * 4) ^ (l16 & 7)) * 8)];
#pragma unroll
      for (int i = 0; i < 4; ++i)
#pragma unroll
        for (int j = 0; j < NJ; ++j)
          acc[i][j] =
              __builtin_amdgcn_mfma_f32_16x16x32_bf16(af[i], bfr[j], acc[i][j], 0, 0, 0);
    }
    __syncthreads();
  }

#pragma unroll
  for (int j = 0; j < NJ; ++j) {
    const int col = n0 + wn + j * 16 + l16;
    const float bv = bias[col >> 3];
#pragma unroll
    for (int i = 0; i < 4; ++i) {
#pragma unroll
      for (int r = 0; r < 4; ++r) {
        const int rw = m0 + wm + i * 16 + quad * 4 + r;
        float vv = acc[i][j][r] + bv;
        if (HAS_RES) vv += res[(size_t)rw * N + col];
        if (OUT_F32)
          ((float*)Yv)[(size_t)rw * N + col] = vv;
        else
          ((u16*)Yv)[(size_t)rw * N + col] = f2b(vv);
      }
    }
  }
}

// fc variants: TN=128 (M>=8192: 512 blocks = 2/CU) and TN=64 fallback.
__global__ __launch_bounds__(256) void gemm_fc128(
    const u16* __restrict__ X, const u16* __restrict__ W,
    const float* __restrict__ bias, const float* __restrict__ res,
    float* __restrict__ Y, int M, int N, int K) {
  gemm_core<128, true, true>(X, W, bias, res, Y, M, N, K, blockIdx.x);
}
__global__ __launch_bounds__(256) void gemm_fc64(
    const u16* __restrict__ X, const u16* __restrict__ W,
    const float* __restrict__ bias, const float* __restrict__ res,
    float* __restrict__ Y, int M, int N, int K) {
  gemm_core<64, true, true>(X, W, bias, res, Y, M, N, K, blockIdx.x);
}

// One wave per (b,h) pair, grid-stride `iters` pairs/wave, no barriers
// (wave-private LDS). V read direct from global (lane-coalesced rows).
// NOTE: o may ALIAS qp (o[pair] overwrites exactly qp[pair], and the o-store
// data-depends on the q-loads of the same pair; pairs are disjoint across
// waves/blocks) -> qp/o are NOT __restrict__.
__global__ __launch_bounds__(256) void attn_kernel(
    const u16* qp, const u16* __restrict__ kp,
    const u16* __restrict__ vp, float* __restrict__ probs,
    u16* o, int iters) {
  __shared__ __align__(16) u16 Qs[4][8 * 72];
  __shared__ __align__(16) u16 Ks[4][8 * 72];
  __shared__ __align__(16) float Ps[4][64];
  const int tid = threadIdx.x;
  const int wave = tid >> 6;
  const int lane = tid & 63;
  const int r = lane >> 3, c = lane & 7;
  const int ls = r * 72 + c * 8;
  const int qg = r;
  const int kg = c;

  auto pairof = [&](int it) { return (it * gridDim.x + blockIdx.x) * 4 + wave; };
  auto gaddr = [&](int it) {
    const int pr = pairof(it);
    return (size_t)(pr >> 3) * 4096 + (size_t)r * 512 + (pr & 7) * 64 + c * 8;
  };

  uint4 qr = *(const uint4*)(qp + gaddr(0));
  uint4 kr = *(const uint4*)(kp + gaddr(0));

  for (int it = 0; it < iters; ++it) {
    *(uint4*)&Qs[wave][ls] = qr;
    *(uint4*)&Ks[wave][ls] = kr;
    const int pair = pairof(it);
    const int b = pair >> 3;
    const int h = pair & 7;
    float vcf[8];
#pragma unroll
    for (int k2 = 0; k2 < 8; ++k2)
      vcf[k2] = b2f(vp[(size_t)b * 4096 + (size_t)k2 * 512 + h * 64 + lane]);
    if (it + 1 < iters) {
      qr = *(const uint4*)(qp + gaddr(it + 1));
      kr = *(const uint4*)(kp + gaddr(it + 1));
    }
    float s = 0.f;
#pragma unroll
    for (int d8 = 0; d8 < 8; ++d8) {
      uint4 qa = *(const uint4*)&Qs[wave][qg * 72 + d8 * 8];
      uint4 ka = *(const uint4*)&Ks[wave][kg * 72 + d8 * 8];
      s += blo(qa.x) * blo(ka.x) + bhi(qa.x) * bhi(ka.x);
      s += blo(qa.y) * blo(ka.y) + bhi(qa.y) * bhi(ka.y);
      s += blo(qa.z) * blo(ka.z) + bhi(qa.z) * bhi(ka.z);
      s += blo(qa.w) * blo(ka.w) + bhi(qa.w) * bhi(ka.w);
    }
    s *= 0.125f;  // 1/sqrt(dk)
    float mx = s;
    mx = fmaxf(mx, __shfl_xor(mx, 1));
    mx = fmaxf(mx, __shfl_xor(mx, 2));
    mx = fmaxf(mx, __shfl_xor(mx, 4));
    float e = __expf(s - mx);
    float sum = e;
    sum += __shfl_xor(sum, 1);
    sum += __shfl_xor(sum, 2);
    sum += __shfl_xor(sum, 4);
    const float p = e / sum;
    probs[(size_t)pair * 64 + lane] = p;
    Ps[wave][lane] = p;  // wave-private, lockstep: no barrier
#pragma unroll
    for (int q2 = 0; q2 < 8; ++q2) {
      float4 p0 = *(const float4*)&Ps[wave][q2 * 8];
      float4 p1 = *(const float4*)&Ps[wave][q2 * 8 + 4];
      float acc = p0.x * vcf[0] + p0.y * vcf[1] + p0.z * vcf[2] + p0.w * vcf[3] +
                  p1.x * vcf[4] + p1.y * vcf[5] + p1.z * vcf[6] + p1.w * vcf[7];
      o[(size_t)b * 4096 + q2 * 512 + h * 64 + lane] = f2b(acc);
    }
  }
}

extern "C" void kernel_launch(void* const* d_in, const int* in_sizes, int n_in,
                              void* d_out, int out_size, void* d_ws, size_t ws_size,
                              hipStream_t stream) {
  const float* q = (const float*)d_in[0];
  const float* k = (const float*)d_in[1];
  const float* v = (const float*)d_in[2];
  const float* w_q = (const float*)d_in[3];
  const float* b_q = (const float*)d_in[4];
  const float* w_k = (const float*)d_in[5];
  const float* b_k = (const float*)d_in[6];
  const float* w_v = (const float*)d_in[7];
  const float* b_v = (const float*)d_in[8];
  const float* w_fc = (const float*)d_in[9];
  const float* b_fc = (const float*)d_in[10];

  const int B = in_sizes[0] / 1024;  // 8192
  float* out = (float*)d_out;                   // B*1024 fp32
  float* probs = out + (size_t)B * 1024;        // B*512 fp32 (attn)

  u16* Wq = (u16*)d_ws;
  u16* Wk = Wq + (size_t)4096 * 1024;
  u16* Wv = Wk + (size_t)4096 * 1024;
  u16* Wfc = Wv + (size_t)4096 * 1024;  // 1024x4096
  u16* qb = Wfc + (size_t)4096 * 1024;  // B x 1024 bf16 inputs
  u16* kb = qb + (size_t)B * 1024;
  u16* vb = kb + (size_t)B * 1024;
  u16* scratch = vb + (size_t)B * 1024;
  const size_t fixed_bytes =
      ((size_t)4 * 4096 * 1024 + (size_t)3 * B * 1024) * sizeof(u16);

  // per-row scratch: qp,kp,vp (ao aliases qp) -> 3 x 4096 bf16 per row
  const size_t per_row = (size_t)(3 * 4096) * sizeof(u16);
  int chunkB = 256;
  for (int c = B; c >= 256; c >>= 1) {
    if (fixed_bytes + (size_t)c * per_row <= ws_size) { chunkB = c; break; }
  }

  u16* qp = scratch;
  u16* kp = qp + (size_t)chunkB * 4096;
  u16* vp = kp + (size_t)chunkB * 4096;
  u16* ao = qp;  // attn output overwrites its own q input (pair-disjoint)

  // expand circulant weights + convert q/k/v to bf16, once per call
  const int cblocks = B / 2;
  expand_all<<<8192 + 3 * cblocks, 256, 0, stream>>>(
      w_q, w_k, w_v, w_fc, q, k, v, Wq, Wk, Wv, Wfc, qb, kb, vb, cblocks);

  for (int cs = 0; cs < B; cs += chunkB) {
    const int nb_p = (chunkB / 256) * (4096 / 256);
    gemm_qkv8p<<<dim3(nb_p, 3), 512, 0, stream>>>(
        qb + (size_t)cs * 1024, kb + (size_t)cs * 1024, vb + (size_t)cs * 1024,
        Wq, Wk, Wv, b_q, b_k, b_v, qp, kp, vp, chunkB, 4096, 1024);
    const int ablocks = (chunkB >= 1024) ? 2048 : chunkB * 2;
    const int aiters = (chunkB * 8) / (ablocks * 4);
    attn_kernel<<<ablocks, 256, 0, stream>>>(qp, kp, vp,
                                             probs + (size_t)cs * 512, ao, aiters);
    if (chunkB >= 8192) {
      const int nb_fc = (chunkB / 128) * (1024 / 128);
      gemm_fc128<<<nb_fc, 256, 0, stream>>>(ao, Wfc, b_fc,
                                            q + (size_t)cs * 1024,
                                            out + (size_t)cs * 1024, chunkB,
                                            1024, 4096);
    } else {
      const int nb_fc = (chunkB / 128) * (1024 / 64);
      gemm_fc64<<<nb_fc, 256, 0, stream>>>(ao, Wfc, b_fc,
                                           q + (size_t)cs * 1024,
                                           out + (size_t)cs * 1024, chunkB,
                                           1024, 4096);
    }
  }
}

// Round 8
// 573.291 us; speedup vs baseline: 1.0498x; 1.0498x over previous
//
#include <hip/hip_runtime.h>
#include <hip/hip_bf16.h>

typedef unsigned short u16;
typedef unsigned int u32;
typedef __bf16 bf16x8_t __attribute__((ext_vector_type(8)));
typedef float f32x4_t __attribute__((ext_vector_type(4)));

__device__ __forceinline__ float b2f(u16 v) {
  return __uint_as_float(((u32)v) << 16);
}
__device__ __forceinline__ u16 f2b(float f) {
  __hip_bfloat16 h = __float2bfloat16(f);
  return *reinterpret_cast<u16*>(&h);
}
__device__ __forceinline__ float blo(u32 u) { return __uint_as_float(u << 16); }
__device__ __forceinline__ float bhi(u32 u) { return __uint_as_float(u & 0xffff0000u); }

__device__ __forceinline__ void async_lds16(const u16* g, u16* l) {
  __builtin_amdgcn_global_load_lds(
      (__attribute__((address_space(1))) void*)g,
      (__attribute__((address_space(3))) void*)l, 16, 0, 0);
}

__device__ __forceinline__ void expand8(const float* __restrict__ w,
                                        u16* __restrict__ dst, int I,
                                        int kshift, int gid) {
  const int n = gid >> kshift;
  const int kc = (gid & ((1 << kshift) - 1)) * 8;
  const int K = 8 << kshift;
  const float* wp = w + (size_t)((n >> 3) * I + (kc >> 3)) * 8;
  float4 w0 = *(const float4*)wp;
  float4 w1 = *(const float4*)(wp + 4);
  float w8[8] = {w0.x, w0.y, w0.z, w0.w, w1.x, w1.y, w1.z, w1.w};
  u16 t[8];
  const int r = (n - kc) & 7;
#pragma unroll
  for (int j = 0; j < 8; ++j) t[j] = f2b(w8[(r - j) & 7]);
  *(uint4*)(dst + (size_t)n * K + kc) = *(const uint4*)t;
}

// fp32 -> bf16, 8 elements per thread, vectorized.
__device__ __forceinline__ void cvt8(const float* __restrict__ src,
                                     u16* __restrict__ dst, int gid) {
  const float* p = src + (size_t)gid * 8;
  float4 a = *(const float4*)p;
  float4 b = *(const float4*)(p + 4);
  u16 t[8] = {f2b(a.x), f2b(a.y), f2b(a.z), f2b(a.w),
              f2b(b.x), f2b(b.y), f2b(b.z), f2b(b.w)};
  *(uint4*)(dst + (size_t)gid * 8) = *(const uint4*)t;
}

// blocks [0,8192): circulant weight expansion (4 weights x 2048 blocks).
// blocks [8192, 8192+3*cblocks): q/k/v fp32->bf16 conversion.
__global__ __launch_bounds__(256) void expand_all(
    const float* __restrict__ w_q, const float* __restrict__ w_k,
    const float* __restrict__ w_v, const float* __restrict__ w_fc,
    const float* __restrict__ q, const float* __restrict__ k,
    const float* __restrict__ v, u16* __restrict__ Wq, u16* __restrict__ Wk,
    u16* __restrict__ Wv, u16* __restrict__ Wfc, u16* __restrict__ qb,
    u16* __restrict__ kb, u16* __restrict__ vb, int cblocks) {
  const int e = blockIdx.x;
  if (e < 8192) {
    const int plane = e >> 11;
    const int gid = (e & 2047) * 256 + threadIdx.x;
    if (plane == 0) expand8(w_q, Wq, 128, 7, gid);
    else if (plane == 1) expand8(w_k, Wk, 128, 7, gid);
    else if (plane == 2) expand8(w_v, Wv, 128, 7, gid);
    else expand8(w_fc, Wfc, 512, 9, gid);
  } else {
    const int ce = e - 8192;
    const int plane = ce / cblocks;
    const int gid = (ce - plane * cblocks) * 256 + threadIdx.x;
    if (plane == 0) cvt8(q, qb, gid);
    else if (plane == 1) cvt8(k, kb, gid);
    else cvt8(v, vb, gid);
  }
}

// ---------------------------------------------------------------------------
// 8-phase 256x256 QKV GEMM (R6, passed). BK=64, 512 thr = 8 waves (2M x 4N).
// vmcnt(4) only at P4/P8.
// R8 change: epilogue uses shfl-packed uint2 stores -> each store instruction
// writes FULL 128B cache lines (4 rows x 16 lanes x 8B), eliminating the
// partial-line write amplification seen as WRITE_SIZE ~2x unique bytes.
// ---------------------------------------------------------------------------
__global__ __launch_bounds__(512, 2) void gemm_qkv8p(
    const u16* __restrict__ X0, const u16* __restrict__ X1,
    const u16* __restrict__ X2, const u16* __restrict__ W0,
    const u16* __restrict__ W1, const u16* __restrict__ W2,
    const float* __restrict__ b0v, const float* __restrict__ b1v,
    const float* __restrict__ b2v, u16* __restrict__ Y0, u16* __restrict__ Y1,
    u16* __restrict__ Y2, int M, int N, int K) {
  __shared__ __align__(16) u16 lds[65536];  // 128 KB
  const int z = blockIdx.y;
  const u16* X = (z == 0) ? X0 : (z == 1) ? X1 : X2;
  const u16* W = (z == 0) ? W0 : (z == 1) ? W1 : W2;
  const float* bias = (z == 0) ? b0v : (z == 1) ? b1v : b2v;
  u16* Y = (z == 0) ? Y0 : (z == 1) ? Y1 : Y2;

  const int tid = threadIdx.x;
  const int bid = blockIdx.x;
  const int grid_m = M >> 8, grid_n = N >> 8;
  const int nb = grid_m * grid_n;
  int pid = (bid & 7) * (nb >> 3) + (bid >> 3);  // XCD-chunked swizzle
  const int nig = 8 * grid_n;
  const int group_id = pid / nig;
  const int first_m = group_id * 8;
  const int gsz = min(8, grid_m - first_m);
  const int mt = first_m + (pid % gsz);
  const int ntile = (pid % nig) / gsz;
  const int m0 = mt << 8, n0 = ntile << 8;

  const int lane = tid & 63, wave = tid >> 6;
  const int wg = wave >> 2;   // m-group: rows wg*128..+127
  const int wq = wave & 3;    // n-group: cols wq*64..+63
  const int l16 = lane & 15, quad = lane >> 4;
  const int lswz = l16 & 7;

  const u16* gA = X + (size_t)m0 * K;
  const u16* gB = W + (size_t)n0 * K;
  const int srow = tid >> 3;                  // 0..63
  const int skbg = (tid & 7) ^ (srow & 7);    // pre-swizzled source k-slot

  f32x4_t acc[8][4] = {};
  const int KT = K >> 6;      // BK=64 tiles (16 for K=1024)
  const int niter = KT >> 1;  // 2 tiles per iteration

  auto stg = [&](int kt, int h, bool isB) {
    u16* l = lds + (isB ? 32768 : 0) + ((kt & 1) * 2 + h) * 8192 + tid * 8;
    const u16* g = (isB ? gB : gA) + (size_t)(h * 128 + srow) * K + kt * 64 +
                   skbg * 8;
    async_lds16(g, l);
    async_lds16(g + (size_t)64 * K, l + 4096);
  };
  auto ldA = [&](int kt, int mh, bf16x8_t (&a)[8]) {
    const u16* base = lds + ((kt & 1) * 2 + wg) * 8192 + (mh * 64 + l16) * 64;
#pragma unroll
    for (int mi = 0; mi < 4; ++mi)
#pragma unroll
      for (int ks = 0; ks < 2; ++ks)
        a[mi * 2 + ks] = *(const bf16x8_t*)(base + mi * 1024 +
                                            (((ks * 4 + quad) ^ lswz) * 8));
  };
  auto ldB = [&](int kt, int nh, bf16x8_t (&b)[4]) {
    const u16* base = lds + 32768 + ((kt & 1) * 2 + (wq >> 1)) * 8192 +
                      ((wq & 1) * 64 + nh * 32 + l16) * 64;
#pragma unroll
    for (int ni = 0; ni < 2; ++ni)
#pragma unroll
      for (int ks = 0; ks < 2; ++ks)
        b[ni * 2 + ks] = *(const bf16x8_t*)(base + ni * 1024 +
                                            (((ks * 4 + quad) ^ lswz) * 8));
  };
  auto mm = [&](int mh, int nh, bf16x8_t (&a)[8], bf16x8_t (&b)[4]) {
    __builtin_amdgcn_s_setprio(1);
#pragma unroll
    for (int mi = 0; mi < 4; ++mi)
#pragma unroll
      for (int ni = 0; ni < 2; ++ni)
#pragma unroll
        for (int ks = 0; ks < 2; ++ks)
          acc[mh * 4 + mi][nh * 2 + ni] = __builtin_amdgcn_mfma_f32_16x16x32_bf16(
              a[mi * 2 + ks], b[ni * 2 + ks], acc[mh * 4 + mi][nh * 2 + ni], 0,
              0, 0);
    __builtin_amdgcn_s_setprio(0);
  };
  auto bar = [] { __builtin_amdgcn_s_barrier(); };
  auto lgkm0 = [] {
    asm volatile("s_waitcnt lgkmcnt(0)" ::: "memory");
    __builtin_amdgcn_sched_barrier(0);
  };
  auto sched = [] { __builtin_amdgcn_sched_barrier(0); };

  bf16x8_t a0[8], a1[8], b0[4], b1[4];

  stg(0, 0, false); sched();
  stg(0, 0, true);  sched();
  stg(0, 1, false); sched();
  stg(0, 1, true);  sched();
  stg(1, 0, true);  sched();
  stg(1, 0, false); sched();
  asm volatile("s_waitcnt vmcnt(4)" ::: "memory");
  bar();
  sched();

  for (int it = 0; it < niter; ++it) {
    const int t = it * 2;
    const bool more = (t + 2 < KT);
    ldA(t, 0, a0); ldB(t, 0, b0);
    stg(t + 1, 1, false);
    sched(); bar(); lgkm0();
    mm(0, 0, a0, b0);
    bar();
    ldB(t, 1, b1);
    stg(t + 1, 1, true);
    sched(); bar(); lgkm0();
    mm(0, 1, a0, b1);
    bar();
    ldA(t, 1, a1);
    if (more) stg(t + 2, 0, true);
    sched(); bar(); lgkm0();
    mm(1, 1, a1, b1);
    bar();
    if (more) stg(t + 2, 0, false);
    sched();
    if (more) asm volatile("s_waitcnt vmcnt(4)" ::: "memory");
    else      asm volatile("s_waitcnt vmcnt(0)" ::: "memory");
    bar(); lgkm0();
    mm(1, 0, a1, b0);
    bar();
    ldA(t + 1, 0, a0); ldB(t + 1, 0, b0);
    if (more) stg(t + 2, 1, false);
    sched(); bar(); lgkm0();
    mm(0, 0, a0, b0);
    bar();
    ldB(t + 1, 1, b1);
    if (more) stg(t + 2, 1, true);
    sched(); bar(); lgkm0();
    mm(0, 1, a0, b1);
    bar();
    ldA(t + 1, 1, a1);
    if (more) stg(t + 3, 0, true);
    sched(); bar(); lgkm0();
    mm(1, 1, a1, b1);
    bar();
    if (more) {
      stg(t + 3, 0, false);
      sched();
      asm volatile("s_waitcnt vmcnt(4)" ::: "memory");
      bar(); lgkm0();
      mm(1, 0, a1, b0);
      bar();
    } else {
      lgkm0();
      mm(1, 0, a1, b0);
    }
  }

  // ---- full-line epilogue ----
  // lane l16 stores cols [4*l16, 4*l16+4) of its quad's 4 rows as uint2:
  // 16 lanes x 8B = one full 128B line per row per instruction.
  // value(R, C): held by lane (quad, C&15) in acc[mi][C>>4][r]; bias folded
  // at the source lane so shfl'd values are final.
#pragma unroll
  for (int mi = 0; mi < 8; ++mi) {
#pragma unroll
    for (int r = 0; r < 4; ++r) {
      const int rw = m0 + wg * 128 + mi * 16 + quad * 4 + r;
      u32 h0, h1, h2, h3;
      {
        const int cb = n0 + wq * 64 + l16;
        h0 = (u32)f2b(acc[mi][0][r] + bias[(cb) >> 3]);
        h1 = (u32)f2b(acc[mi][1][r] + bias[(cb + 16) >> 3]);
        h2 = (u32)f2b(acc[mi][2][r] + bias[(cb + 32) >> 3]);
        h3 = (u32)f2b(acc[mi][3][r] + bias[(cb + 48) >> 3]);
      }
      const int s0 = quad * 16 + 4 * (l16 & 3);
      u32 g0[4], g1[4], g2[4], g3[4];
#pragma unroll
      for (int j = 0; j < 4; ++j) {
        g0[j] = (u32)__shfl((int)h0, s0 + j);
        g1[j] = (u32)__shfl((int)h1, s0 + j);
        g2[j] = (u32)__shfl((int)h2, s0 + j);
        g3[j] = (u32)__shfl((int)h3, s0 + j);
      }
      const int myni = l16 >> 2;  // 0..3
      u32 a_[4];
#pragma unroll
      for (int j = 0; j < 4; ++j) {
        u32 s01 = (myni & 1) ? g1[j] : g0[j];
        u32 s23 = (myni & 1) ? g3[j] : g2[j];
        a_[j] = (myni & 2) ? s23 : s01;
      }
      uint2 wv;
      wv.x = a_[0] | (a_[1] << 16);
      wv.y = a_[2] | (a_[3] << 16);
      *(uint2*)&Y[(size_t)rw * N + n0 + wq * 64 + 4 * l16] = wv;
    }
  }
}

// ---------------------------------------------------------------------------
// fc GEMM: R5/R6-verified deep-pipelined structure, 128x128 tile, BK=32.
// ---------------------------------------------------------------------------
template <int TM, int TN, bool HAS_RES, bool OUT_F32>
__device__ __forceinline__ void gemm_pipe(
    const u16* __restrict__ X, const u16* __restrict__ W,
    const float* __restrict__ bias, const float* __restrict__ res,
    void* __restrict__ Yv, int M, int N, int K, int bid) {
  constexpr int LDS_A = TM * 32;
  constexpr int BUF = (TM + TN) * 32;
  constexpr int APASS = TM / 128, BPASS = TN / 128;
  constexpr int LPT = APASS + BPASS;
  constexpr int NJ = TN / 64;
  constexpr int FH = TM / 64;
  __shared__ __align__(16) u16 lds[4 * BUF];

  const int tid = threadIdx.x;
  const int grid_m = M / TM, grid_n = N / TN;
  const int nb = grid_m * grid_n;
  int pid = (bid & 7) * (nb >> 3) + (bid >> 3);
  const int nig = 8 * grid_n;
  const int group_id = pid / nig;
  const int first_m = group_id * 8;
  const int gsz = min(8, grid_m - first_m);
  const int mt = first_m + (pid % gsz);
  const int ntile = (pid % nig) / gsz;
  const int m0 = mt * TM, n0 = ntile * TN;

  const int lane = tid & 63, wave = tid >> 6;
  const int wm = (wave >> 2) * (TM / 2);
  const int wn = (wave & 3) * (TN / 4);
  const int l16 = lane & 15, quad = lane >> 4;
  const int kbl = quad ^ ((l16 >> 1) & 3);

  const int srow = tid >> 2;
  const int skbg = (tid & 3) ^ ((tid >> 3) & 3);
  const u16* pA = X + (size_t)(m0 + srow) * K + skbg * 8;
  const u16* pB = W + (size_t)(n0 + srow) * K + skbg * 8;
  const size_t rskip = (size_t)128 * K;

  const int aoff = (wm + l16) * 32 + kbl * 8;
  const int boff = LDS_A + (wn + l16) * 32 + kbl * 8;

  f32x4_t acc[2 * FH][NJ] = {};
  const int nt = K >> 5;

  auto stage = [&](int t) {
    u16* l = lds + (t & 3) * BUF;
    const u16* a = pA + t * 32;
    const u16* b = pB + t * 32;
#pragma unroll
    for (int p = 0; p < APASS; ++p)
      async_lds16(a + p * rskip, l + tid * 8 + p * 4096);
#pragma unroll
    for (int p = 0; p < BPASS; ++p)
      async_lds16(b + p * rskip, l + LDS_A + tid * 8 + p * 4096);
  };

#define WAIT_VM_LPT()                                              \
  do {                                                             \
    if constexpr (LPT == 4)                                        \
      asm volatile("s_waitcnt vmcnt(4)" ::: "memory");             \
    else if constexpr (LPT == 3)                                   \
      asm volatile("s_waitcnt vmcnt(3)" ::: "memory");             \
    else                                                           \
      asm volatile("s_waitcnt vmcnt(2)" ::: "memory");             \
  } while (0)

  bf16x8_t A0[FH], A1[FH], Bc[NJ], Bn[NJ];

  stage(0);
  __builtin_amdgcn_sched_barrier(0);
  stage(1);
  __builtin_amdgcn_sched_barrier(0);
  stage(2);
  WAIT_VM_LPT();
  __builtin_amdgcn_s_barrier();
  __builtin_amdgcn_sched_barrier(0);

  {
    const u16* la = lds + aoff;
    const u16* lb = lds + boff;
#pragma unroll
    for (int mi = 0; mi < FH; ++mi) A0[mi] = *(const bf16x8_t*)(la + mi * 512);
#pragma unroll
    for (int ni = 0; ni < NJ; ++ni) Bc[ni] = *(const bf16x8_t*)(lb + ni * 512);
  }

  auto body = [&](int t, bf16x8_t (&BCUR)[NJ], bf16x8_t (&BNXT)[NJ]) {
    if (t + 3 < nt) stage(t + 3);
    const u16* lc = lds + (t & 3) * BUF;
    const u16* ln = lds + ((t + 1) & 3) * BUF;
#pragma unroll
    for (int mi = 0; mi < FH; ++mi)
      A1[mi] = *(const bf16x8_t*)(lc + aoff + (mi + FH) * 512);
    if (t + 1 < nt) {
#pragma unroll
      for (int ni = 0; ni < NJ; ++ni)
        BNXT[ni] = *(const bf16x8_t*)(ln + boff + ni * 512);
    }
    __builtin_amdgcn_s_setprio(1);
#pragma unroll
    for (int mi = 0; mi < FH; ++mi)
#pragma unroll
      for (int ni = 0; ni < NJ; ++ni)
        acc[mi][ni] = __builtin_amdgcn_mfma_f32_16x16x32_bf16(
            A0[mi], BCUR[ni], acc[mi][ni], 0, 0, 0);
    __builtin_amdgcn_s_setprio(0);
    if (t + 1 < nt) {
#pragma unroll
      for (int mi = 0; mi < FH; ++mi)
        A0[mi] = *(const bf16x8_t*)(ln + aoff + mi * 512);
    }
    __builtin_amdgcn_s_setprio(1);
#pragma unroll
    for (int mi = 0; mi < FH; ++mi)
#pragma unroll
      for (int ni = 0; ni < NJ; ++ni)
        acc[mi + FH][ni] = __builtin_amdgcn_mfma_f32_16x16x32_bf16(
            A1[mi], BCUR[ni], acc[mi + FH][ni], 0, 0, 0);
    __builtin_amdgcn_s_setprio(0);
    if (t + 1 < nt) {
      asm volatile("s_waitcnt lgkmcnt(0)" ::: "memory");
      __builtin_amdgcn_sched_barrier(0);
      if (t + 3 < nt) WAIT_VM_LPT();
      else            asm volatile("s_waitcnt vmcnt(0)" ::: "memory");
      __builtin_amdgcn_s_barrier();
      __builtin_amdgcn_sched_barrier(0);
    }
  };

  for (int t = 0; t < nt; t += 2) {
    body(t, Bc, Bn);
    body(t + 1, Bn, Bc);
  }
#undef WAIT_VM_LPT

#pragma unroll
  for (int ni = 0; ni < NJ; ++ni) {
    const int col = n0 + wn + ni * 16 + l16;
    const float bv = bias[col >> 3];
#pragma unroll
    for (int mi = 0; mi < 2 * FH; ++mi) {
#pragma unroll
      for (int r = 0; r < 4; ++r) {
        const int rw = m0 + wm + mi * 16 + quad * 4 + r;
        float vv = acc[mi][ni][r] + bv;
        if (HAS_RES) vv += res[(size_t)rw * N + col];
        if (OUT_F32)
          ((float*)Yv)[(size_t)rw * N + col] = vv;
        else
          ((u16*)Yv)[(size_t)rw * N + col] = f2b(vv);
      }
    }
  }
}

// fc: 128x128 tile -> 256 blocks at M=4096 (1/CU), K=4096 deep.
__global__ __launch_bounds__(512, 2) void gemm_fc(
    const u16* __restrict__ X, const u16* __restrict__ W,
    const float* __restrict__ bias, const float* __restrict__ res,
    float* __restrict__ Y, int M, int N, int K) {
  gemm_pipe<128, 128, true, true>(X, W, bias, res, Y, M, N, K, blockIdx.x);
}

// One wave per (b,h) pair, grid-stride `iters` pairs/wave, no barriers
// (wave-private LDS). V read direct from global (lane-coalesced rows).
__global__ __launch_bounds__(256) void attn_kernel(
    const u16* __restrict__ qp, const u16* __restrict__ kp,
    const u16* __restrict__ vp, float* __restrict__ probs,
    u16* __restrict__ o, int iters) {
  __shared__ __align__(16) u16 Qs[4][8 * 72];
  __shared__ __align__(16) u16 Ks[4][8 * 72];
  __shared__ __align__(16) float Ps[4][64];
  const int tid = threadIdx.x;
  const int wave = tid >> 6;
  const int lane = tid & 63;
  const int r = lane >> 3, c = lane & 7;
  const int ls = r * 72 + c * 8;
  const int qg = r;
  const int kg = c;

  auto pairof = [&](int it) { return (it * gridDim.x + blockIdx.x) * 4 + wave; };
  auto gaddr = [&](int it) {
    const int pr = pairof(it);
    return (size_t)(pr >> 3) * 4096 + (size_t)r * 512 + (pr & 7) * 64 + c * 8;
  };

  uint4 qr = *(const uint4*)(qp + gaddr(0));
  uint4 kr = *(const uint4*)(kp + gaddr(0));

  for (int it = 0; it < iters; ++it) {
    *(uint4*)&Qs[wave][ls] = qr;
    *(uint4*)&Ks[wave][ls] = kr;
    const int pair = pairof(it);
    const int b = pair >> 3;
    const int h = pair & 7;
    float vcf[8];
#pragma unroll
    for (int k2 = 0; k2 < 8; ++k2)
      vcf[k2] = b2f(vp[(size_t)b * 4096 + (size_t)k2 * 512 + h * 64 + lane]);
    if (it + 1 < iters) {
      qr = *(const uint4*)(qp + gaddr(it + 1));
      kr = *(const uint4*)(kp + gaddr(it + 1));
    }
    float s = 0.f;
#pragma unroll
    for (int d8 = 0; d8 < 8; ++d8) {
      uint4 qa = *(const uint4*)&Qs[wave][qg * 72 + d8 * 8];
      uint4 ka = *(const uint4*)&Ks[wave][kg * 72 + d8 * 8];
      s += blo(qa.x) * blo(ka.x) + bhi(qa.x) * bhi(ka.x);
      s += blo(qa.y) * blo(ka.y) + bhi(qa.y) * bhi(ka.y);
      s += blo(qa.z) * blo(ka.z) + bhi(qa.z) * bhi(ka.z);
      s += blo(qa.w) * blo(ka.w) + bhi(qa.w) * bhi(ka.w);
    }
    s *= 0.125f;  // 1/sqrt(dk)
    float mx = s;
    mx = fmaxf(mx, __shfl_xor(mx, 1));
    mx = fmaxf(mx, __shfl_xor(mx, 2));
    mx = fmaxf(mx, __shfl_xor(mx, 4));
    float e = __expf(s - mx);
    float sum = e;
    sum += __shfl_xor(sum, 1);
    sum += __shfl_xor(sum, 2);
    sum += __shfl_xor(sum, 4);
    const float p = e / sum;
    probs[(size_t)pair * 64 + lane] = p;
    Ps[wave][lane] = p;  // wave-private, lockstep: no barrier
#pragma unroll
    for (int q2 = 0; q2 < 8; ++q2) {
      float4 p0 = *(const float4*)&Ps[wave][q2 * 8];
      float4 p1 = *(const float4*)&Ps[wave][q2 * 8 + 4];
      float acc = p0.x * vcf[0] + p0.y * vcf[1] + p0.z * vcf[2] + p0.w * vcf[3] +
                  p1.x * vcf[4] + p1.y * vcf[5] + p1.z * vcf[6] + p1.w * vcf[7];
      o[(size_t)b * 4096 + q2 * 512 + h * 64 + lane] = f2b(acc);
    }
  }
}

extern "C" void kernel_launch(void* const* d_in, const int* in_sizes, int n_in,
                              void* d_out, int out_size, void* d_ws, size_t ws_size,
                              hipStream_t stream) {
  const float* q = (const float*)d_in[0];
  const float* k = (const float*)d_in[1];
  const float* v = (const float*)d_in[2];
  const float* w_q = (const float*)d_in[3];
  const float* b_q = (const float*)d_in[4];
  const float* w_k = (const float*)d_in[5];
  const float* b_k = (const float*)d_in[6];
  const float* w_v = (const float*)d_in[7];
  const float* b_v = (const float*)d_in[8];
  const float* w_fc = (const float*)d_in[9];
  const float* b_fc = (const float*)d_in[10];

  const int B = in_sizes[0] / 1024;  // 8192
  float* out = (float*)d_out;                   // B*1024 fp32
  float* probs = out + (size_t)B * 1024;        // B*512 fp32 (attn)

  u16* Wq = (u16*)d_ws;
  u16* Wk = Wq + (size_t)4096 * 1024;
  u16* Wv = Wk + (size_t)4096 * 1024;
  u16* Wfc = Wv + (size_t)4096 * 1024;  // 1024x4096
  u16* qb = Wfc + (size_t)4096 * 1024;  // B x 1024 bf16 inputs
  u16* kb = qb + (size_t)B * 1024;
  u16* vb = kb + (size_t)B * 1024;
  u16* scratch = vb + (size_t)B * 1024;
  const size_t fixed_bytes =
      ((size_t)4 * 4096 * 1024 + (size_t)3 * B * 1024) * sizeof(u16);

  // per-row scratch: qp,kp,vp,ao (4096 each), bf16
  const size_t per_row = (size_t)(4 * 4096) * sizeof(u16);
  int chunkB = 256;
  for (int c = B; c >= 256; c >>= 1) {
    if (fixed_bytes + (size_t)c * per_row <= ws_size) { chunkB = c; break; }
  }

  u16* qp = scratch;
  u16* kp = qp + (size_t)chunkB * 4096;
  u16* vp = kp + (size_t)chunkB * 4096;
  u16* ao = vp + (size_t)chunkB * 4096;

  // expand circulant weights + convert q/k/v to bf16, once per call
  const int cblocks = B / 2;
  expand_all<<<8192 + 3 * cblocks, 256, 0, stream>>>(
      w_q, w_k, w_v, w_fc, q, k, v, Wq, Wk, Wv, Wfc, qb, kb, vb, cblocks);

  for (int cs = 0; cs < B; cs += chunkB) {
    const int nb_p = (chunkB / 256) * (4096 / 256);
    gemm_qkv8p<<<dim3(nb_p, 3), 512, 0, stream>>>(
        qb + (size_t)cs * 1024, kb + (size_t)cs * 1024, vb + (size_t)cs * 1024,
        Wq, Wk, Wv, b_q, b_k, b_v, qp, kp, vp, chunkB, 4096, 1024);
    const int ablocks = (chunkB >= 1024) ? 2048 : chunkB * 2;
    const int aiters = (chunkB * 8) / (ablocks * 4);
    attn_kernel<<<ablocks, 256, 0, stream>>>(qp, kp, vp,
                                             probs + (size_t)cs * 512, ao, aiters);
    const int nb_fc = (chunkB / 128) * (1024 / 128);
    gemm_fc<<<nb_fc, 512, 0, stream>>>(ao, Wfc, b_fc, q + (size_t)cs * 1024,
                                       out + (size_t)cs * 1024, chunkB, 1024,
                                       4096);
  }
}

// Round 9
// 570.205 us; speedup vs baseline: 1.0554x; 1.0054x over previous
//
#include <hip/hip_runtime.h>
#include <hip/hip_bf16.h>

typedef unsigned short u16;
typedef unsigned int u32;
typedef __bf16 bf16x8_t __attribute__((ext_vector_type(8)));
typedef float f32x4_t __attribute__((ext_vector_type(4)));

#define BK 64

__device__ __forceinline__ float b2f(u16 v) {
  return __uint_as_float(((u32)v) << 16);
}
__device__ __forceinline__ u16 f2b(float f) {
  __hip_bfloat16 h = __float2bfloat16(f);
  return *reinterpret_cast<u16*>(&h);
}
__device__ __forceinline__ float blo(u32 u) { return __uint_as_float(u << 16); }
__device__ __forceinline__ float bhi(u32 u) { return __uint_as_float(u & 0xffff0000u); }

__device__ __forceinline__ void async_lds16(const u16* g, u16* l) {
  __builtin_amdgcn_global_load_lds(
      (__attribute__((address_space(1))) void*)g,
      (__attribute__((address_space(3))) void*)l, 16, 0, 0);
}

__device__ __forceinline__ void expand8(const float* __restrict__ w,
                                        u16* __restrict__ dst, int I,
                                        int kshift, int gid) {
  const int n = gid >> kshift;
  const int kc = (gid & ((1 << kshift) - 1)) * 8;
  const int K = 8 << kshift;
  const float* wp = w + (size_t)((n >> 3) * I + (kc >> 3)) * 8;
  float4 w0 = *(const float4*)wp;
  float4 w1 = *(const float4*)(wp + 4);
  float w8[8] = {w0.x, w0.y, w0.z, w0.w, w1.x, w1.y, w1.z, w1.w};
  u16 t[8];
  const int r = (n - kc) & 7;
#pragma unroll
  for (int j = 0; j < 8; ++j) t[j] = f2b(w8[(r - j) & 7]);
  *(uint4*)(dst + (size_t)n * K + kc) = *(const uint4*)t;
}

// fp32 -> bf16, 8 elements per thread, vectorized.
__device__ __forceinline__ void cvt8(const float* __restrict__ src,
                                     u16* __restrict__ dst, int gid) {
  const float* p = src + (size_t)gid * 8;
  float4 a = *(const float4*)p;
  float4 b = *(const float4*)(p + 4);
  u16 t[8] = {f2b(a.x), f2b(a.y), f2b(a.z), f2b(a.w),
              f2b(b.x), f2b(b.y), f2b(b.z), f2b(b.w)};
  *(uint4*)(dst + (size_t)gid * 8) = *(const uint4*)t;
}

// blocks [0,8192): circulant weight expansion (4 weights x 2048 blocks).
// blocks [8192, 8192+3*cblocks): q/k/v fp32->bf16 conversion.
__global__ __launch_bounds__(256) void expand_all(
    const float* __restrict__ w_q, const float* __restrict__ w_k,
    const float* __restrict__ w_v, const float* __restrict__ w_fc,
    const float* __restrict__ q, const float* __restrict__ k,
    const float* __restrict__ v, u16* __restrict__ Wq, u16* __restrict__ Wk,
    u16* __restrict__ Wv, u16* __restrict__ Wfc, u16* __restrict__ qb,
    u16* __restrict__ kb, u16* __restrict__ vb, int cblocks) {
  const int e = blockIdx.x;
  if (e < 8192) {
    const int plane = e >> 11;
    const int gid = (e & 2047) * 256 + threadIdx.x;
    if (plane == 0) expand8(w_q, Wq, 128, 7, gid);
    else if (plane == 1) expand8(w_k, Wk, 128, 7, gid);
    else if (plane == 2) expand8(w_v, Wv, 128, 7, gid);
    else expand8(w_fc, Wfc, 512, 9, gid);
  } else {
    const int ce = e - 8192;
    const int plane = ce / cblocks;
    const int gid = (ce - plane * cblocks) * 256 + threadIdx.x;
    if (plane == 0) cvt8(q, qb, gid);
    else if (plane == 1) cvt8(k, kb, gid);
    else cvt8(v, vb, gid);
  }
}

// ---------------------------------------------------------------------------
// 8-phase 256x256 QKV GEMM (R8, passed; shfl-packed full-line epilogue).
// BK=64, 512 thr = 8 waves (2M x 4N). vmcnt(4) only at P4/P8.
// ---------------------------------------------------------------------------
__global__ __launch_bounds__(512, 2) void gemm_qkv8p(
    const u16* __restrict__ X0, const u16* __restrict__ X1,
    const u16* __restrict__ X2, const u16* __restrict__ W0,
    const u16* __restrict__ W1, const u16* __restrict__ W2,
    const float* __restrict__ b0v, const float* __restrict__ b1v,
    const float* __restrict__ b2v, u16* __restrict__ Y0, u16* __restrict__ Y1,
    u16* __restrict__ Y2, int M, int N, int K) {
  __shared__ __align__(16) u16 lds[65536];  // 128 KB
  const int z = blockIdx.y;
  const u16* X = (z == 0) ? X0 : (z == 1) ? X1 : X2;
  const u16* W = (z == 0) ? W0 : (z == 1) ? W1 : W2;
  const float* bias = (z == 0) ? b0v : (z == 1) ? b1v : b2v;
  u16* Y = (z == 0) ? Y0 : (z == 1) ? Y1 : Y2;

  const int tid = threadIdx.x;
  const int bid = blockIdx.x;
  const int grid_m = M >> 8, grid_n = N >> 8;
  const int nb = grid_m * grid_n;
  int pid = (bid & 7) * (nb >> 3) + (bid >> 3);  // XCD-chunked swizzle
  const int nig = 8 * grid_n;
  const int group_id = pid / nig;
  const int first_m = group_id * 8;
  const int gsz = min(8, grid_m - first_m);
  const int mt = first_m + (pid % gsz);
  const int ntile = (pid % nig) / gsz;
  const int m0 = mt << 8, n0 = ntile << 8;

  const int lane = tid & 63, wave = tid >> 6;
  const int wg = wave >> 2;   // m-group: rows wg*128..+127
  const int wq = wave & 3;    // n-group: cols wq*64..+63
  const int l16 = lane & 15, quad = lane >> 4;
  const int lswz = l16 & 7;

  const u16* gA = X + (size_t)m0 * K;
  const u16* gB = W + (size_t)n0 * K;
  const int srow = tid >> 3;                  // 0..63
  const int skbg = (tid & 7) ^ (srow & 7);    // pre-swizzled source k-slot

  f32x4_t acc[8][4] = {};
  const int KT = K >> 6;      // BK=64 tiles (16 for K=1024)
  const int niter = KT >> 1;  // 2 tiles per iteration

  auto stg = [&](int kt, int h, bool isB) {
    u16* l = lds + (isB ? 32768 : 0) + ((kt & 1) * 2 + h) * 8192 + tid * 8;
    const u16* g = (isB ? gB : gA) + (size_t)(h * 128 + srow) * K + kt * 64 +
                   skbg * 8;
    async_lds16(g, l);
    async_lds16(g + (size_t)64 * K, l + 4096);
  };
  auto ldA = [&](int kt, int mh, bf16x8_t (&a)[8]) {
    const u16* base = lds + ((kt & 1) * 2 + wg) * 8192 + (mh * 64 + l16) * 64;
#pragma unroll
    for (int mi = 0; mi < 4; ++mi)
#pragma unroll
      for (int ks = 0; ks < 2; ++ks)
        a[mi * 2 + ks] = *(const bf16x8_t*)(base + mi * 1024 +
                                            (((ks * 4 + quad) ^ lswz) * 8));
  };
  auto ldB = [&](int kt, int nh, bf16x8_t (&b)[4]) {
    const u16* base = lds + 32768 + ((kt & 1) * 2 + (wq >> 1)) * 8192 +
                      ((wq & 1) * 64 + nh * 32 + l16) * 64;
#pragma unroll
    for (int ni = 0; ni < 2; ++ni)
#pragma unroll
      for (int ks = 0; ks < 2; ++ks)
        b[ni * 2 + ks] = *(const bf16x8_t*)(base + ni * 1024 +
                                            (((ks * 4 + quad) ^ lswz) * 8));
  };
  auto mm = [&](int mh, int nh, bf16x8_t (&a)[8], bf16x8_t (&b)[4]) {
    __builtin_amdgcn_s_setprio(1);
#pragma unroll
    for (int mi = 0; mi < 4; ++mi)
#pragma unroll
      for (int ni = 0; ni < 2; ++ni)
#pragma unroll
        for (int ks = 0; ks < 2; ++ks)
          acc[mh * 4 + mi][nh * 2 + ni] = __builtin_amdgcn_mfma_f32_16x16x32_bf16(
              a[mi * 2 + ks], b[ni * 2 + ks], acc[mh * 4 + mi][nh * 2 + ni], 0,
              0, 0);
    __builtin_amdgcn_s_setprio(0);
  };
  auto bar = [] { __builtin_amdgcn_s_barrier(); };
  auto lgkm0 = [] {
    asm volatile("s_waitcnt lgkmcnt(0)" ::: "memory");
    __builtin_amdgcn_sched_barrier(0);
  };
  auto sched = [] { __builtin_amdgcn_sched_barrier(0); };

  bf16x8_t a0[8], a1[8], b0[4], b1[4];

  stg(0, 0, false); sched();
  stg(0, 0, true);  sched();
  stg(0, 1, false); sched();
  stg(0, 1, true);  sched();
  stg(1, 0, true);  sched();
  stg(1, 0, false); sched();
  asm volatile("s_waitcnt vmcnt(4)" ::: "memory");
  bar();
  sched();

  for (int it = 0; it < niter; ++it) {
    const int t = it * 2;
    const bool more = (t + 2 < KT);
    ldA(t, 0, a0); ldB(t, 0, b0);
    stg(t + 1, 1, false);
    sched(); bar(); lgkm0();
    mm(0, 0, a0, b0);
    bar();
    ldB(t, 1, b1);
    stg(t + 1, 1, true);
    sched(); bar(); lgkm0();
    mm(0, 1, a0, b1);
    bar();
    ldA(t, 1, a1);
    if (more) stg(t + 2, 0, true);
    sched(); bar(); lgkm0();
    mm(1, 1, a1, b1);
    bar();
    if (more) stg(t + 2, 0, false);
    sched();
    if (more) asm volatile("s_waitcnt vmcnt(4)" ::: "memory");
    else      asm volatile("s_waitcnt vmcnt(0)" ::: "memory");
    bar(); lgkm0();
    mm(1, 0, a1, b0);
    bar();
    ldA(t + 1, 0, a0); ldB(t + 1, 0, b0);
    if (more) stg(t + 2, 1, false);
    sched(); bar(); lgkm0();
    mm(0, 0, a0, b0);
    bar();
    ldB(t + 1, 1, b1);
    if (more) stg(t + 2, 1, true);
    sched(); bar(); lgkm0();
    mm(0, 1, a0, b1);
    bar();
    ldA(t + 1, 1, a1);
    if (more) stg(t + 3, 0, true);
    sched(); bar(); lgkm0();
    mm(1, 1, a1, b1);
    bar();
    if (more) {
      stg(t + 3, 0, false);
      sched();
      asm volatile("s_waitcnt vmcnt(4)" ::: "memory");
      bar(); lgkm0();
      mm(1, 0, a1, b0);
      bar();
    } else {
      lgkm0();
      mm(1, 0, a1, b0);
    }
  }

  // full-line epilogue: lane l16 stores cols [4*l16,4*l16+4) as uint2 ->
  // 16 lanes x 8B = one full 128B line per row per instruction.
#pragma unroll
  for (int mi = 0; mi < 8; ++mi) {
#pragma unroll
    for (int r = 0; r < 4; ++r) {
      const int rw = m0 + wg * 128 + mi * 16 + quad * 4 + r;
      u32 h0, h1, h2, h3;
      {
        const int cb = n0 + wq * 64 + l16;
        h0 = (u32)f2b(acc[mi][0][r] + bias[(cb) >> 3]);
        h1 = (u32)f2b(acc[mi][1][r] + bias[(cb + 16) >> 3]);
        h2 = (u32)f2b(acc[mi][2][r] + bias[(cb + 32) >> 3]);
        h3 = (u32)f2b(acc[mi][3][r] + bias[(cb + 48) >> 3]);
      }
      const int s0 = quad * 16 + 4 * (l16 & 3);
      u32 g0[4], g1[4], g2[4], g3[4];
#pragma unroll
      for (int j = 0; j < 4; ++j) {
        g0[j] = (u32)__shfl((int)h0, s0 + j);
        g1[j] = (u32)__shfl((int)h1, s0 + j);
        g2[j] = (u32)__shfl((int)h2, s0 + j);
        g3[j] = (u32)__shfl((int)h3, s0 + j);
      }
      const int myni = l16 >> 2;  // 0..3
      u32 a_[4];
#pragma unroll
      for (int j = 0; j < 4; ++j) {
        u32 s01 = (myni & 1) ? g1[j] : g0[j];
        u32 s23 = (myni & 1) ? g3[j] : g2[j];
        a_[j] = (myni & 2) ? s23 : s01;
      }
      uint2 wv;
      wv.x = a_[0] | (a_[1] << 16);
      wv.y = a_[2] | (a_[3] << 16);
      *(uint2*)&Y[(size_t)rw * N + n0 + wq * 64 + 4 * l16] = wv;
    }
  }
}

// ---------------------------------------------------------------------------
// fc GEMM: R0-proven 2-barrier structure, TILE_M=128, TILE_N=128, BK=64,
// 256 thr, 32KB LDS. Runs ONCE at M=8192 -> 512 blocks = 2/CU.
// Dual A pointers: rows [0,halfM) from A0, rows [halfM,M) from A1
// (attn outputs of chunk0/chunk1 live in different buffers).
// ---------------------------------------------------------------------------
__global__ __launch_bounds__(256) void gemm_fc2(
    const u16* __restrict__ Aa, const u16* __restrict__ Ab,
    const u16* __restrict__ W, const float* __restrict__ bias,
    const float* __restrict__ res, float* __restrict__ Y, int M, int N, int K,
    int halfM) {
  constexpr int TN = 128;
  __shared__ __align__(16) u16 As[128 * BK];
  __shared__ __align__(16) u16 Bs[TN * BK];
  const int tid = threadIdx.x;
  const int bid = blockIdx.x;

  const int grid_m = M >> 7, grid_n = N / TN;
  const int nb = grid_m * grid_n;
  int pid = (bid & 7) * (nb >> 3) + (bid >> 3);
  const int nig = 8 * grid_n;
  const int group_id = pid / nig;
  const int first_m = group_id * 8;
  const int gsz = min(8, grid_m - first_m);
  const int mt = first_m + (pid % gsz);
  const int nt = (pid % nig) / gsz;
  const int m0 = mt << 7, n0 = nt * TN;

  const u16* Xb = (m0 < halfM) ? Aa : Ab;
  const int m0l = (m0 < halfM) ? m0 : m0 - halfM;

  const int lane = tid & 63;
  const int wave = tid >> 6;
  const int wm = (wave >> 1) * 64;
  const int wn = (wave & 1) * (TN / 2);
  const int l16 = lane & 15;
  const int quad = lane >> 4;
  constexpr int NJ = TN >> 5;

  f32x4_t acc[4][NJ] = {};

  const int row0 = tid >> 3;
  const int kgl = ((tid & 7) ^ (row0 & 7)) * 8;

  for (int k0 = 0; k0 < K; k0 += BK) {
#pragma unroll
    for (int it = 0; it < TN / 32; ++it)
      async_lds16(W + (size_t)(n0 + row0 + it * 32) * K + (k0 + kgl),
                  &Bs[(tid + it * 256) * 8]);
#pragma unroll
    for (int it = 0; it < 4; ++it)
      async_lds16(Xb + (size_t)(m0l + row0 + it * 32) * K + (k0 + kgl),
                  &As[(tid + it * 256) * 8]);
    __syncthreads();
#pragma unroll
    for (int half = 0; half < 2; ++half) {
      bf16x8_t af[4], bfr[NJ];
#pragma unroll
      for (int i = 0; i < 4; ++i)
        af[i] = *(const bf16x8_t*)&As[(wm + i * 16 + l16) * BK +
                                      (((quad + half * 4) ^ (l16 & 7)) * 8)];
#pragma unroll
      for (int j = 0; j < NJ; ++j)
        bfr[j] = *(const bf16x8_t*)&Bs[(wn + j * 16 + l16) * BK +
                                       (((quad + half * 4) ^ (l16 & 7)) * 8)];
#pragma unroll
      for (int i = 0; i < 4; ++i)
#pragma unroll
        for (int j = 0; j < NJ; ++j)
          acc[i][j] =
              __builtin_amdgcn_mfma_f32_16x16x32_bf16(af[i], bfr[j], acc[i][j], 0, 0, 0);
    }
    __syncthreads();
  }

#pragma unroll
  for (int i = 0; i < 4; ++i) {
#pragma unroll
    for (int r = 0; r < 4; ++r) {
      const int rw = m0 + wm + i * 16 + quad * 4 + r;
#pragma unroll
      for (int j = 0; j < NJ; ++j) {
        const int col = n0 + wn + j * 16 + l16;
        float vv = acc[i][j][r] + bias[col >> 3] + res[(size_t)rw * N + col];
        Y[(size_t)rw * N + col] = vv;
      }
    }
  }
}

// One wave per (b,h) pair, grid-stride `iters` pairs/wave, no barriers
// (wave-private LDS). V loaded as one uint4/lane + LDS transpose.
// NOTE: o may ALIAS vp (each pair reads exactly its own V slice before
// writing exactly its own O slice; cross-iteration prefetches touch
// different, disjoint pairs) -> vp/o are NOT __restrict__.
__global__ __launch_bounds__(256) void attn_kernel(
    const u16* __restrict__ qp, const u16* __restrict__ kp, const u16* vp,
    float* __restrict__ probs, u16* o, int iters) {
  __shared__ __align__(16) u16 Qs[4][8 * 72];
  __shared__ __align__(16) u16 Ks[4][8 * 72];
  __shared__ __align__(16) u16 Vs[4][512];
  __shared__ __align__(16) float Ps[4][64];
  const int tid = threadIdx.x;
  const int wave = tid >> 6;
  const int lane = tid & 63;
  const int r = lane >> 3, c = lane & 7;
  const int ls = r * 72 + c * 8;
  const int qg = r;
  const int kg = c;

  auto pairof = [&](int it) { return (it * gridDim.x + blockIdx.x) * 4 + wave; };
  auto gaddr = [&](int it) {
    const int pr = pairof(it);
    return (size_t)(pr >> 3) * 4096 + (size_t)r * 512 + (pr & 7) * 64 + c * 8;
  };
  // lane loads 8 contiguous u16 of V row k2=lane>>3, cols (lane&7)*8..+8
  auto vaddr = [&](int it) {
    const int pr = pairof(it);
    return (size_t)(pr >> 3) * 4096 + (size_t)(lane >> 3) * 512 +
           (pr & 7) * 64 + (lane & 7) * 8;
  };

  uint4 qr = *(const uint4*)(qp + gaddr(0));
  uint4 kr = *(const uint4*)(kp + gaddr(0));
  uint4 vr = *(const uint4*)(vp + vaddr(0));

  for (int it = 0; it < iters; ++it) {
    *(uint4*)&Qs[wave][ls] = qr;
    *(uint4*)&Ks[wave][ls] = kr;
    *(uint4*)&Vs[wave][lane * 8] = vr;
    const int pair = pairof(it);
    const int b = pair >> 3;
    const int h = pair & 7;
    if (it + 1 < iters) {
      qr = *(const uint4*)(qp + gaddr(it + 1));
      kr = *(const uint4*)(kp + gaddr(it + 1));
      vr = *(const uint4*)(vp + vaddr(it + 1));
    }
    float s = 0.f;
#pragma unroll
    for (int d8 = 0; d8 < 8; ++d8) {
      uint4 qa = *(const uint4*)&Qs[wave][qg * 72 + d8 * 8];
      uint4 ka = *(const uint4*)&Ks[wave][kg * 72 + d8 * 8];
      s += blo(qa.x) * blo(ka.x) + bhi(qa.x) * bhi(ka.x);
      s += blo(qa.y) * blo(ka.y) + bhi(qa.y) * bhi(ka.y);
      s += blo(qa.z) * blo(ka.z) + bhi(qa.z) * bhi(ka.z);
      s += blo(qa.w) * blo(ka.w) + bhi(qa.w) * bhi(ka.w);
    }
    s *= 0.125f;  // 1/sqrt(dk)
    float mx = s;
    mx = fmaxf(mx, __shfl_xor(mx, 1));
    mx = fmaxf(mx, __shfl_xor(mx, 2));
    mx = fmaxf(mx, __shfl_xor(mx, 4));
    float e = __expf(s - mx);
    float sum = e;
    sum += __shfl_xor(sum, 1);
    sum += __shfl_xor(sum, 2);
    sum += __shfl_xor(sum, 4);
    const float p = e / sum;
    probs[(size_t)pair * 64 + lane] = p;
    Ps[wave][lane] = p;  // wave-private, lockstep: no barrier
    float vcf[8];
#pragma unroll
    for (int k2 = 0; k2 < 8; ++k2)
      vcf[k2] = b2f(Vs[wave][k2 * 64 + lane]);
#pragma unroll
    for (int q2 = 0; q2 < 8; ++q2) {
      float4 p0 = *(const float4*)&Ps[wave][q2 * 8];
      float4 p1 = *(const float4*)&Ps[wave][q2 * 8 + 4];
      float acc = p0.x * vcf[0] + p0.y * vcf[1] + p0.z * vcf[2] + p0.w * vcf[3] +
                  p1.x * vcf[4] + p1.y * vcf[5] + p1.z * vcf[6] + p1.w * vcf[7];
      o[(size_t)b * 4096 + q2 * 512 + h * 64 + lane] = f2b(acc);
    }
  }
}

extern "C" void kernel_launch(void* const* d_in, const int* in_sizes, int n_in,
                              void* d_out, int out_size, void* d_ws, size_t ws_size,
                              hipStream_t stream) {
  const float* q = (const float*)d_in[0];
  const float* k = (const float*)d_in[1];
  const float* v = (const float*)d_in[2];
  const float* w_q = (const float*)d_in[3];
  const float* b_q = (const float*)d_in[4];
  const float* w_k = (const float*)d_in[5];
  const float* b_k = (const float*)d_in[6];
  const float* w_v = (const float*)d_in[7];
  const float* b_v = (const float*)d_in[8];
  const float* w_fc = (const float*)d_in[9];
  const float* b_fc = (const float*)d_in[10];

  const int B = in_sizes[0] / 1024;  // 8192
  float* out = (float*)d_out;                   // B*1024 fp32
  float* probs = out + (size_t)B * 1024;        // B*512 fp32 (attn)

  u16* Wq = (u16*)d_ws;
  u16* Wk = Wq + (size_t)4096 * 1024;
  u16* Wv = Wk + (size_t)4096 * 1024;
  u16* Wfc = Wv + (size_t)4096 * 1024;  // 1024x4096
  u16* qb = Wfc + (size_t)4096 * 1024;  // B x 1024 bf16 inputs
  u16* kb = qb + (size_t)B * 1024;
  u16* vb = kb + (size_t)B * 1024;
  u16* scratch = vb + (size_t)B * 1024;
  const size_t fixed_bytes =
      ((size_t)4 * 4096 * 1024 + (size_t)3 * B * 1024) * sizeof(u16);

  // per-row scratch: qp,kp,vp,ao0 (4096 each), bf16 -- same footprint as R8.
  const size_t per_row = (size_t)(4 * 4096) * sizeof(u16);
  int chunkB = 256;
  for (int c = B; c >= 256; c >>= 1) {
    if (fixed_bytes + (size_t)c * per_row <= ws_size) { chunkB = c; break; }
  }

  u16* qp = scratch;
  u16* kp = qp + (size_t)chunkB * 4096;
  u16* vp = kp + (size_t)chunkB * 4096;
  u16* ao0 = vp + (size_t)chunkB * 4096;  // chunk0 attn out (dedicated)

  // expand circulant weights + convert q/k/v to bf16, once per call
  const int cblocks = B / 2;
  expand_all<<<8192 + 3 * cblocks, 256, 0, stream>>>(
      w_q, w_k, w_v, w_fc, q, k, v, Wq, Wk, Wv, Wfc, qb, kb, vb, cblocks);

  const bool two_chunks = (chunkB * 2 == B);
  for (int cs = 0; cs < B; cs += chunkB) {
    const int nb_p = (chunkB / 256) * (4096 / 256);
    gemm_qkv8p<<<dim3(nb_p, 3), 512, 0, stream>>>(
        qb + (size_t)cs * 1024, kb + (size_t)cs * 1024, vb + (size_t)cs * 1024,
        Wq, Wk, Wv, b_q, b_k, b_v, qp, kp, vp, chunkB, 4096, 1024);
    const int ablocks = (chunkB >= 1024) ? 2048 : chunkB * 2;
    const int aiters = (chunkB * 8) / (ablocks * 4);
    // chunk0 -> dedicated ao0; chunk1 -> alias onto vp (pair-disjoint, safe)
    u16* aoc = (cs == 0) ? ao0 : vp;
    attn_kernel<<<ablocks, 256, 0, stream>>>(qp, kp, vp,
                                             probs + (size_t)cs * 512, aoc,
                                             aiters);
    if (!two_chunks) {
      // fallback: per-chunk fc (should not trigger at known ws sizes)
      const int nb_fc = (chunkB / 128) * (1024 / 128);
      gemm_fc2<<<nb_fc, 256, 0, stream>>>(aoc, aoc, Wfc, b_fc,
                                          q + (size_t)cs * 1024,
                                          out + (size_t)cs * 1024, chunkB, 1024,
                                          4096, chunkB);
    }
  }
  if (two_chunks) {
    // single fc over both halves: M=8192 -> 512 blocks = 2 blocks/CU
    const int nb_fc = (B / 128) * (1024 / 128);
    gemm_fc2<<<nb_fc, 256, 0, stream>>>(ao0, vp, Wfc, b_fc, q, out, B, 1024,
                                        4096, chunkB);
  }
}

// Round 10
// 547.983 us; speedup vs baseline: 1.0982x; 1.0406x over previous
//
#include <hip/hip_runtime.h>
#include <hip/hip_bf16.h>

typedef unsigned short u16;
typedef unsigned int u32;
typedef __bf16 bf16x8_t __attribute__((ext_vector_type(8)));
typedef float f32x4_t __attribute__((ext_vector_type(4)));

#define BK 64

__device__ __forceinline__ float b2f(u16 v) {
  return __uint_as_float(((u32)v) << 16);
}
__device__ __forceinline__ u16 f2b(float f) {
  __hip_bfloat16 h = __float2bfloat16(f);
  return *reinterpret_cast<u16*>(&h);
}
__device__ __forceinline__ float blo(u32 u) { return __uint_as_float(u << 16); }
__device__ __forceinline__ float bhi(u32 u) { return __uint_as_float(u & 0xffff0000u); }

__device__ __forceinline__ void async_lds16(const u16* g, u16* l) {
  __builtin_amdgcn_global_load_lds(
      (__attribute__((address_space(1))) void*)g,
      (__attribute__((address_space(3))) void*)l, 16, 0, 0);
}

__device__ __forceinline__ void expand8(const float* __restrict__ w,
                                        u16* __restrict__ dst, int I,
                                        int kshift, int gid) {
  const int n = gid >> kshift;
  const int kc = (gid & ((1 << kshift) - 1)) * 8;
  const int K = 8 << kshift;
  const float* wp = w + (size_t)((n >> 3) * I + (kc >> 3)) * 8;
  float4 w0 = *(const float4*)wp;
  float4 w1 = *(const float4*)(wp + 4);
  float w8[8] = {w0.x, w0.y, w0.z, w0.w, w1.x, w1.y, w1.z, w1.w};
  u16 t[8];
  const int r = (n - kc) & 7;
#pragma unroll
  for (int j = 0; j < 8; ++j) t[j] = f2b(w8[(r - j) & 7]);
  *(uint4*)(dst + (size_t)n * K + kc) = *(const uint4*)t;
}

// fp32 -> bf16, 8 elements per thread, vectorized.
__device__ __forceinline__ void cvt8(const float* __restrict__ src,
                                     u16* __restrict__ dst, int gid) {
  const float* p = src + (size_t)gid * 8;
  float4 a = *(const float4*)p;
  float4 b = *(const float4*)(p + 4);
  u16 t[8] = {f2b(a.x), f2b(a.y), f2b(a.z), f2b(a.w),
              f2b(b.x), f2b(b.y), f2b(b.z), f2b(b.w)};
  *(uint4*)(dst + (size_t)gid * 8) = *(const uint4*)t;
}

// blocks [0,8192): circulant weight expansion (4 weights x 2048 blocks).
// blocks [8192, 8192+3*cblocks): q/k/v fp32->bf16 conversion.
__global__ __launch_bounds__(256) void expand_all(
    const float* __restrict__ w_q, const float* __restrict__ w_k,
    const float* __restrict__ w_v, const float* __restrict__ w_fc,
    const float* __restrict__ q, const float* __restrict__ k,
    const float* __restrict__ v, u16* __restrict__ Wq, u16* __restrict__ Wk,
    u16* __restrict__ Wv, u16* __restrict__ Wfc, u16* __restrict__ qb,
    u16* __restrict__ kb, u16* __restrict__ vb, int cblocks) {
  const int e = blockIdx.x;
  if (e < 8192) {
    const int plane = e >> 11;
    const int gid = (e & 2047) * 256 + threadIdx.x;
    if (plane == 0) expand8(w_q, Wq, 128, 7, gid);
    else if (plane == 1) expand8(w_k, Wk, 128, 7, gid);
    else if (plane == 2) expand8(w_v, Wv, 128, 7, gid);
    else expand8(w_fc, Wfc, 512, 9, gid);
  } else {
    const int ce = e - 8192;
    const int plane = ce / cblocks;
    const int gid = (ce - plane * cblocks) * 256 + threadIdx.x;
    if (plane == 0) cvt8(q, qb, gid);
    else if (plane == 1) cvt8(k, kb, gid);
    else cvt8(v, vb, gid);
  }
}

// ---------------------------------------------------------------------------
// 8-phase 256x256 QKV GEMM (R8, passed; shfl-packed full-line epilogue).
// BK=64, 512 thr = 8 waves (2M x 4N). vmcnt(4) only at P4/P8.
// ---------------------------------------------------------------------------
__global__ __launch_bounds__(512, 2) void gemm_qkv8p(
    const u16* __restrict__ X0, const u16* __restrict__ X1,
    const u16* __restrict__ X2, const u16* __restrict__ W0,
    const u16* __restrict__ W1, const u16* __restrict__ W2,
    const float* __restrict__ b0v, const float* __restrict__ b1v,
    const float* __restrict__ b2v, u16* __restrict__ Y0, u16* __restrict__ Y1,
    u16* __restrict__ Y2, int M, int N, int K) {
  __shared__ __align__(16) u16 lds[65536];  // 128 KB
  const int z = blockIdx.y;
  const u16* X = (z == 0) ? X0 : (z == 1) ? X1 : X2;
  const u16* W = (z == 0) ? W0 : (z == 1) ? W1 : W2;
  const float* bias = (z == 0) ? b0v : (z == 1) ? b1v : b2v;
  u16* Y = (z == 0) ? Y0 : (z == 1) ? Y1 : Y2;

  const int tid = threadIdx.x;
  const int bid = blockIdx.x;
  const int grid_m = M >> 8, grid_n = N >> 8;
  const int nb = grid_m * grid_n;
  int pid = (bid & 7) * (nb >> 3) + (bid >> 3);  // XCD-chunked swizzle
  const int nig = 8 * grid_n;
  const int group_id = pid / nig;
  const int first_m = group_id * 8;
  const int gsz = min(8, grid_m - first_m);
  const int mt = first_m + (pid % gsz);
  const int ntile = (pid % nig) / gsz;
  const int m0 = mt << 8, n0 = ntile << 8;

  const int lane = tid & 63, wave = tid >> 6;
  const int wg = wave >> 2;   // m-group: rows wg*128..+127
  const int wq = wave & 3;    // n-group: cols wq*64..+63
  const int l16 = lane & 15, quad = lane >> 4;
  const int lswz = l16 & 7;

  const u16* gA = X + (size_t)m0 * K;
  const u16* gB = W + (size_t)n0 * K;
  const int srow = tid >> 3;                  // 0..63
  const int skbg = (tid & 7) ^ (srow & 7);    // pre-swizzled source k-slot

  f32x4_t acc[8][4] = {};
  const int KT = K >> 6;      // BK=64 tiles (16 for K=1024)
  const int niter = KT >> 1;  // 2 tiles per iteration

  auto stg = [&](int kt, int h, bool isB) {
    u16* l = lds + (isB ? 32768 : 0) + ((kt & 1) * 2 + h) * 8192 + tid * 8;
    const u16* g = (isB ? gB : gA) + (size_t)(h * 128 + srow) * K + kt * 64 +
                   skbg * 8;
    async_lds16(g, l);
    async_lds16(g + (size_t)64 * K, l + 4096);
  };
  auto ldA = [&](int kt, int mh, bf16x8_t (&a)[8]) {
    const u16* base = lds + ((kt & 1) * 2 + wg) * 8192 + (mh * 64 + l16) * 64;
#pragma unroll
    for (int mi = 0; mi < 4; ++mi)
#pragma unroll
      for (int ks = 0; ks < 2; ++ks)
        a[mi * 2 + ks] = *(const bf16x8_t*)(base + mi * 1024 +
                                            (((ks * 4 + quad) ^ lswz) * 8));
  };
  auto ldB = [&](int kt, int nh, bf16x8_t (&b)[4]) {
    const u16* base = lds + 32768 + ((kt & 1) * 2 + (wq >> 1)) * 8192 +
                      ((wq & 1) * 64 + nh * 32 + l16) * 64;
#pragma unroll
    for (int ni = 0; ni < 2; ++ni)
#pragma unroll
      for (int ks = 0; ks < 2; ++ks)
        b[ni * 2 + ks] = *(const bf16x8_t*)(base + ni * 1024 +
                                            (((ks * 4 + quad) ^ lswz) * 8));
  };
  auto mm = [&](int mh, int nh, bf16x8_t (&a)[8], bf16x8_t (&b)[4]) {
    __builtin_amdgcn_s_setprio(1);
#pragma unroll
    for (int mi = 0; mi < 4; ++mi)
#pragma unroll
      for (int ni = 0; ni < 2; ++ni)
#pragma unroll
        for (int ks = 0; ks < 2; ++ks)
          acc[mh * 4 + mi][nh * 2 + ni] = __builtin_amdgcn_mfma_f32_16x16x32_bf16(
              a[mi * 2 + ks], b[ni * 2 + ks], acc[mh * 4 + mi][nh * 2 + ni], 0,
              0, 0);
    __builtin_amdgcn_s_setprio(0);
  };
  auto bar = [] { __builtin_amdgcn_s_barrier(); };
  auto lgkm0 = [] {
    asm volatile("s_waitcnt lgkmcnt(0)" ::: "memory");
    __builtin_amdgcn_sched_barrier(0);
  };
  auto sched = [] { __builtin_amdgcn_sched_barrier(0); };

  bf16x8_t a0[8], a1[8], b0[4], b1[4];

  stg(0, 0, false); sched();
  stg(0, 0, true);  sched();
  stg(0, 1, false); sched();
  stg(0, 1, true);  sched();
  stg(1, 0, true);  sched();
  stg(1, 0, false); sched();
  asm volatile("s_waitcnt vmcnt(4)" ::: "memory");
  bar();
  sched();

  for (int it = 0; it < niter; ++it) {
    const int t = it * 2;
    const bool more = (t + 2 < KT);
    ldA(t, 0, a0); ldB(t, 0, b0);
    stg(t + 1, 1, false);
    sched(); bar(); lgkm0();
    mm(0, 0, a0, b0);
    bar();
    ldB(t, 1, b1);
    stg(t + 1, 1, true);
    sched(); bar(); lgkm0();
    mm(0, 1, a0, b1);
    bar();
    ldA(t, 1, a1);
    if (more) stg(t + 2, 0, true);
    sched(); bar(); lgkm0();
    mm(1, 1, a1, b1);
    bar();
    if (more) stg(t + 2, 0, false);
    sched();
    if (more) asm volatile("s_waitcnt vmcnt(4)" ::: "memory");
    else      asm volatile("s_waitcnt vmcnt(0)" ::: "memory");
    bar(); lgkm0();
    mm(1, 0, a1, b0);
    bar();
    ldA(t + 1, 0, a0); ldB(t + 1, 0, b0);
    if (more) stg(t + 2, 1, false);
    sched(); bar(); lgkm0();
    mm(0, 0, a0, b0);
    bar();
    ldB(t + 1, 1, b1);
    if (more) stg(t + 2, 1, true);
    sched(); bar(); lgkm0();
    mm(0, 1, a0, b1);
    bar();
    ldA(t + 1, 1, a1);
    if (more) stg(t + 3, 0, true);
    sched(); bar(); lgkm0();
    mm(1, 1, a1, b1);
    bar();
    if (more) {
      stg(t + 3, 0, false);
      sched();
      asm volatile("s_waitcnt vmcnt(4)" ::: "memory");
      bar(); lgkm0();
      mm(1, 0, a1, b0);
      bar();
    } else {
      lgkm0();
      mm(1, 0, a1, b0);
    }
  }

  // full-line epilogue: lane l16 stores cols [4*l16,4*l16+4) as uint2 ->
  // 16 lanes x 8B = one full 128B line per row per instruction.
#pragma unroll
  for (int mi = 0; mi < 8; ++mi) {
#pragma unroll
    for (int r = 0; r < 4; ++r) {
      const int rw = m0 + wg * 128 + mi * 16 + quad * 4 + r;
      u32 h0, h1, h2, h3;
      {
        const int cb = n0 + wq * 64 + l16;
        h0 = (u32)f2b(acc[mi][0][r] + bias[(cb) >> 3]);
        h1 = (u32)f2b(acc[mi][1][r] + bias[(cb + 16) >> 3]);
        h2 = (u32)f2b(acc[mi][2][r] + bias[(cb + 32) >> 3]);
        h3 = (u32)f2b(acc[mi][3][r] + bias[(cb + 48) >> 3]);
      }
      const int s0 = quad * 16 + 4 * (l16 & 3);
      u32 g0[4], g1[4], g2[4], g3[4];
#pragma unroll
      for (int j = 0; j < 4; ++j) {
        g0[j] = (u32)__shfl((int)h0, s0 + j);
        g1[j] = (u32)__shfl((int)h1, s0 + j);
        g2[j] = (u32)__shfl((int)h2, s0 + j);
        g3[j] = (u32)__shfl((int)h3, s0 + j);
      }
      const int myni = l16 >> 2;  // 0..3
      u32 a_[4];
#pragma unroll
      for (int j = 0; j < 4; ++j) {
        u32 s01 = (myni & 1) ? g1[j] : g0[j];
        u32 s23 = (myni & 1) ? g3[j] : g2[j];
        a_[j] = (myni & 2) ? s23 : s01;
      }
      uint2 wv;
      wv.x = a_[0] | (a_[1] << 16);
      wv.y = a_[2] | (a_[3] << 16);
      *(uint2*)&Y[(size_t)rw * N + n0 + wq * 64 + 4 * l16] = wv;
    }
  }
}

// ---------------------------------------------------------------------------
// fc 8-phase braid: 256x128 tile, BK=64, 512 thr = 8 waves (2M x 4N),
// per-wave 128x32 out, acc[8][2]. Geometry port of gemm_qkv8p (passed R6-R9):
// B half-tile = 64 rows -> 1 load/thread (A = 2) -> 6 loads/tile -> all
// gates vmcnt(3). LDS 96KB. Grid at M=8192: 32x8 = 256 blocks = 1/CU.
// Dual A (chunk0 in Aa, chunk1 in Ab). fp32 out = bias + residual,
// shfl-gathered float2 stores (16 lanes x 8B = full 128B line).
// ---------------------------------------------------------------------------
__global__ __launch_bounds__(512, 2) void gemm_fc8p(
    const u16* __restrict__ Aa, const u16* __restrict__ Ab,
    const u16* __restrict__ W, const float* __restrict__ bias,
    const float* __restrict__ res, float* __restrict__ Y, int M, int N, int K,
    int halfM) {
  __shared__ __align__(16) u16 lds[49152];  // 96 KB: A 64KB + B 32KB
  const int tid = threadIdx.x;
  const int bid = blockIdx.x;
  const int grid_m = M >> 8, grid_n = N >> 7;
  const int nb = grid_m * grid_n;
  int pid = (bid & 7) * (nb >> 3) + (bid >> 3);  // XCD-chunked swizzle
  const int nig = 8 * grid_n;
  const int group_id = pid / nig;
  const int first_m = group_id * 8;
  const int gsz = min(8, grid_m - first_m);
  const int mt = first_m + (pid % gsz);
  const int ntile = (pid % nig) / gsz;
  const int m0 = mt << 8, n0 = ntile << 7;

  const u16* Xb = (m0 < halfM) ? Aa : Ab;
  const int m0l = (m0 < halfM) ? m0 : m0 - halfM;

  const int lane = tid & 63, wave = tid >> 6;
  const int wg = wave >> 2;   // m-group: rows wg*128..+127
  const int wq = wave & 3;    // n-group: cols wq*32..+31
  const int l16 = lane & 15, quad = lane >> 4;
  const int lswz = l16 & 7;

  const u16* gA = Xb + (size_t)m0l * K;
  const u16* gB = W + (size_t)n0 * K;
  const int srow = tid >> 3;                  // 0..63
  const int skbg = (tid & 7) ^ (srow & 7);    // pre-swizzled source k-slot

  f32x4_t acc[8][2] = {};
  const int KT = K >> 6;      // 64 tiles for K=4096
  const int niter = KT >> 1;

  // A half = 128 rows (2 loads/thread); B half = 64 rows (1 load/thread)
  auto stgA = [&](int kt, int h) {
    u16* l = lds + ((kt & 1) * 2 + h) * 8192 + tid * 8;
    const u16* g = gA + (size_t)(h * 128 + srow) * K + kt * 64 + skbg * 8;
    async_lds16(g, l);
    async_lds16(g + (size_t)64 * K, l + 4096);
  };
  auto stgB = [&](int kt, int h) {
    u16* l = lds + 32768 + ((kt & 1) * 2 + h) * 4096 + tid * 8;
    const u16* g = gB + (size_t)(h * 64 + srow) * K + kt * 64 + skbg * 8;
    async_lds16(g, l);
  };
  auto ldA = [&](int kt, int mh, bf16x8_t (&a)[8]) {
    const u16* base = lds + ((kt & 1) * 2 + wg) * 8192 + (mh * 64 + l16) * 64;
#pragma unroll
    for (int mi = 0; mi < 4; ++mi)
#pragma unroll
      for (int ks = 0; ks < 2; ++ks)
        a[mi * 2 + ks] = *(const bf16x8_t*)(base + mi * 1024 +
                                            (((ks * 4 + quad) ^ lswz) * 8));
  };
  // wave reads B rows (wq*32 + nh*16 + l16) within the 128-col tile:
  // staged half = wq>>1, offset in half = (wq&1)*32 + nh*16 + l16.
  auto ldB = [&](int kt, int nh, bf16x8_t (&b)[2]) {
    const u16* base = lds + 32768 + ((kt & 1) * 2 + (wq >> 1)) * 4096 +
                      ((wq & 1) * 32 + nh * 16 + l16) * 64;
#pragma unroll
    for (int ks = 0; ks < 2; ++ks)
      b[ks] = *(const bf16x8_t*)(base + (((ks * 4 + quad) ^ lswz) * 8));
  };
  auto mm = [&](int mh, int nh, bf16x8_t (&a)[8], bf16x8_t (&b)[2]) {
    __builtin_amdgcn_s_setprio(1);
#pragma unroll
    for (int mi = 0; mi < 4; ++mi)
#pragma unroll
      for (int ks = 0; ks < 2; ++ks)
        acc[mh * 4 + mi][nh] = __builtin_amdgcn_mfma_f32_16x16x32_bf16(
            a[mi * 2 + ks], b[ks], acc[mh * 4 + mi][nh], 0, 0, 0);
    __builtin_amdgcn_s_setprio(0);
  };
  auto bar = [] { __builtin_amdgcn_s_barrier(); };
  auto lgkm0 = [] {
    asm volatile("s_waitcnt lgkmcnt(0)" ::: "memory");
    __builtin_amdgcn_sched_barrier(0);
  };
  auto sched = [] { __builtin_amdgcn_sched_barrier(0); };

  bf16x8_t a0[8], a1[8], b0[2], b1[2];

  // prologue: tile0 all halves (6 loads), then (1,B0)=1, (1,A0)=2.
  // vmcnt(3) -> tile0 landed.
  stgA(0, 0); sched();
  stgB(0, 0); sched();
  stgA(0, 1); sched();
  stgB(0, 1); sched();
  stgB(1, 0); sched();
  stgA(1, 0); sched();
  asm volatile("s_waitcnt vmcnt(3)" ::: "memory");
  bar();
  sched();

  for (int it = 0; it < niter; ++it) {
    const int t = it * 2;
    const bool more = (t + 2 < KT);
    // P1: Q(t,0,0); stage (t+1,A1)
    ldA(t, 0, a0); ldB(t, 0, b0);
    stgA(t + 1, 1);
    sched(); bar(); lgkm0();
    mm(0, 0, a0, b0);
    bar();
    // P2: Q(t,0,1); stage (t+1,B1)
    ldB(t, 1, b1);
    stgB(t + 1, 1);
    sched(); bar(); lgkm0();
    mm(0, 1, a0, b1);
    bar();
    // P3: Q(t,1,1); stage (t+2,B0)
    ldA(t, 1, a1);
    if (more) stgB(t + 2, 0);
    sched(); bar(); lgkm0();
    mm(1, 1, a1, b1);
    bar();
    // P4: Q(t,1,0); stage (t+2,A0); gate tile t+1
    if (more) stgA(t + 2, 0);
    sched();
    if (more) asm volatile("s_waitcnt vmcnt(3)" ::: "memory");
    else      asm volatile("s_waitcnt vmcnt(0)" ::: "memory");
    bar(); lgkm0();
    mm(1, 0, a1, b0);
    bar();
    // P5: Q(t+1,0,0); stage (t+2,A1)
    ldA(t + 1, 0, a0); ldB(t + 1, 0, b0);
    if (more) stgA(t + 2, 1);
    sched(); bar(); lgkm0();
    mm(0, 0, a0, b0);
    bar();
    // P6: Q(t+1,0,1); stage (t+2,B1)
    ldB(t + 1, 1, b1);
    if (more) stgB(t + 2, 1);
    sched(); bar(); lgkm0();
    mm(0, 1, a0, b1);
    bar();
    // P7: Q(t+1,1,1); stage (t+3,B0)
    ldA(t + 1, 1, a1);
    if (more) stgB(t + 3, 0);
    sched(); bar(); lgkm0();
    mm(1, 1, a1, b1);
    bar();
    // P8: Q(t+1,1,0); stage (t+3,A0); gate tile t+2
    if (more) {
      stgA(t + 3, 0);
      sched();
      asm volatile("s_waitcnt vmcnt(3)" ::: "memory");
      bar(); lgkm0();
      mm(1, 0, a1, b0);
      bar();
    } else {
      lgkm0();
      mm(1, 0, a1, b0);
    }
  }

  // epilogue: gather 2 adjacent cols/lane via shfl, add bias+residual,
  // store float2 -> 16 lanes x 8B = one full 128B line per row.
#pragma unroll
  for (int mi = 0; mi < 8; ++mi) {
#pragma unroll
    for (int r = 0; r < 4; ++r) {
      const int rw = m0 + wg * 128 + mi * 16 + quad * 4 + r;
      const float h0 = acc[mi][0][r];
      const float h1 = acc[mi][1][r];
      const int c0 = 2 * l16, c1 = 2 * l16 + 1;
      const int ls0 = quad * 16 + (c0 & 15);
      const int ls1 = quad * 16 + (c1 & 15);
      float s00 = __shfl(h0, ls0), s01 = __shfl(h1, ls0);
      float s10 = __shfl(h0, ls1), s11 = __shfl(h1, ls1);
      float v0 = (c0 & 16) ? s01 : s00;
      float v1 = (c1 & 16) ? s11 : s10;
      const int col0 = n0 + wq * 32 + c0;
      const size_t base = (size_t)rw * N + col0;
      float2 rr = *(const float2*)&res[base];
      v0 += bias[col0 >> 3] + rr.x;
      v1 += bias[(col0 + 1) >> 3] + rr.y;
      float2 wv; wv.x = v0; wv.y = v1;
      *(float2*)&Y[base] = wv;
    }
  }
}

// ---------------------------------------------------------------------------
// fallback fc (2-barrier gemm_core, TN=128) -- only if chunking != 2.
// ---------------------------------------------------------------------------
__global__ __launch_bounds__(256) void gemm_fc2(
    const u16* __restrict__ Aa, const u16* __restrict__ Ab,
    const u16* __restrict__ W, const float* __restrict__ bias,
    const float* __restrict__ res, float* __restrict__ Y, int M, int N, int K,
    int halfM) {
  constexpr int TN = 128;
  __shared__ __align__(16) u16 As[128 * BK];
  __shared__ __align__(16) u16 Bs[TN * BK];
  const int tid = threadIdx.x;
  const int bid = blockIdx.x;

  const int grid_m = M >> 7, grid_n = N / TN;
  const int nb = grid_m * grid_n;
  int pid = (bid & 7) * (nb >> 3) + (bid >> 3);
  const int nig = 8 * grid_n;
  const int group_id = pid / nig;
  const int first_m = group_id * 8;
  const int gsz = min(8, grid_m - first_m);
  const int mt = first_m + (pid % gsz);
  const int nt = (pid % nig) / gsz;
  const int m0 = mt << 7, n0 = nt * TN;

  const u16* Xb = (m0 < halfM) ? Aa : Ab;
  const int m0l = (m0 < halfM) ? m0 : m0 - halfM;

  const int lane = tid & 63;
  const int wave = tid >> 6;
  const int wm = (wave >> 1) * 64;
  const int wn = (wave & 1) * (TN / 2);
  const int l16 = lane & 15;
  const int quad = lane >> 4;
  constexpr int NJ = TN >> 5;

  f32x4_t acc[4][NJ] = {};

  const int row0 = tid >> 3;
  const int kgl = ((tid & 7) ^ (row0 & 7)) * 8;

  for (int k0 = 0; k0 < K; k0 += BK) {
#pragma unroll
    for (int it = 0; it < TN / 32; ++it)
      async_lds16(W + (size_t)(n0 + row0 + it * 32) * K + (k0 + kgl),
                  &Bs[(tid + it * 256) * 8]);
#pragma unroll
    for (int it = 0; it < 4; ++it)
      async_lds16(Xb + (size_t)(m0l + row0 + it * 32) * K + (k0 + kgl),
                  &As[(tid + it * 256) * 8]);
    __syncthreads();
#pragma unroll
    for (int half = 0; half < 2; ++half) {
      bf16x8_t af[4], bfr[NJ];
#pragma unroll
      for (int i = 0; i < 4; ++i)
        af[i] = *(const bf16x8_t*)&As[(wm + i * 16 + l16) * BK +
                                      (((quad + half * 4) ^ (l16 & 7)) * 8)];
#pragma unroll
      for (int j = 0; j < NJ; ++j)
        bfr[j] = *(const bf16x8_t*)&Bs[(wn + j * 16 + l16) * BK +
                                       (((quad + half * 4) ^ (l16 & 7)) * 8)];
#pragma unroll
      for (int i = 0; i < 4; ++i)
#pragma unroll
        for (int j = 0; j < NJ; ++j)
          acc[i][j] =
              __builtin_amdgcn_mfma_f32_16x16x32_bf16(af[i], bfr[j], acc[i][j], 0, 0, 0);
    }
    __syncthreads();
  }

#pragma unroll
  for (int i = 0; i < 4; ++i) {
#pragma unroll
    for (int r = 0; r < 4; ++r) {
      const int rw = m0 + wm + i * 16 + quad * 4 + r;
#pragma unroll
      for (int j = 0; j < NJ; ++j) {
        const int col = n0 + wn + j * 16 + l16;
        float vv = acc[i][j][r] + bias[col >> 3] + res[(size_t)rw * N + col];
        Y[(size_t)rw * N + col] = vv;
      }
    }
  }
}

// One wave per (b,h) pair, grid-stride `iters` pairs/wave, no barriers
// (wave-private LDS). V loaded as one uint4/lane + LDS transpose.
// NOTE: o may ALIAS vp (each pair reads exactly its own V slice before
// writing exactly its own O slice; cross-iteration prefetches touch
// different, disjoint pairs) -> vp/o are NOT __restrict__.
__global__ __launch_bounds__(256) void attn_kernel(
    const u16* __restrict__ qp, const u16* __restrict__ kp, const u16* vp,
    float* __restrict__ probs, u16* o, int iters) {
  __shared__ __align__(16) u16 Qs[4][8 * 72];
  __shared__ __align__(16) u16 Ks[4][8 * 72];
  __shared__ __align__(16) u16 Vs[4][512];
  __shared__ __align__(16) float Ps[4][64];
  const int tid = threadIdx.x;
  const int wave = tid >> 6;
  const int lane = tid & 63;
  const int r = lane >> 3, c = lane & 7;
  const int ls = r * 72 + c * 8;
  const int qg = r;
  const int kg = c;

  auto pairof = [&](int it) { return (it * gridDim.x + blockIdx.x) * 4 + wave; };
  auto gaddr = [&](int it) {
    const int pr = pairof(it);
    return (size_t)(pr >> 3) * 4096 + (size_t)r * 512 + (pr & 7) * 64 + c * 8;
  };
  auto vaddr = [&](int it) {
    const int pr = pairof(it);
    return (size_t)(pr >> 3) * 4096 + (size_t)(lane >> 3) * 512 +
           (pr & 7) * 64 + (lane & 7) * 8;
  };

  uint4 qr = *(const uint4*)(qp + gaddr(0));
  uint4 kr = *(const uint4*)(kp + gaddr(0));
  uint4 vr = *(const uint4*)(vp + vaddr(0));

  for (int it = 0; it < iters; ++it) {
    *(uint4*)&Qs[wave][ls] = qr;
    *(uint4*)&Ks[wave][ls] = kr;
    *(uint4*)&Vs[wave][lane * 8] = vr;
    const int pair = pairof(it);
    const int b = pair >> 3;
    const int h = pair & 7;
    if (it + 1 < iters) {
      qr = *(const uint4*)(qp + gaddr(it + 1));
      kr = *(const uint4*)(kp + gaddr(it + 1));
      vr = *(const uint4*)(vp + vaddr(it + 1));
    }
    float s = 0.f;
#pragma unroll
    for (int d8 = 0; d8 < 8; ++d8) {
      uint4 qa = *(const uint4*)&Qs[wave][qg * 72 + d8 * 8];
      uint4 ka = *(const uint4*)&Ks[wave][kg * 72 + d8 * 8];
      s += blo(qa.x) * blo(ka.x) + bhi(qa.x) * bhi(ka.x);
      s += blo(qa.y) * blo(ka.y) + bhi(qa.y) * bhi(ka.y);
      s += blo(qa.z) * blo(ka.z) + bhi(qa.z) * bhi(ka.z);
      s += blo(qa.w) * blo(ka.w) + bhi(qa.w) * bhi(ka.w);
    }
    s *= 0.125f;  // 1/sqrt(dk)
    float mx = s;
    mx = fmaxf(mx, __shfl_xor(mx, 1));
    mx = fmaxf(mx, __shfl_xor(mx, 2));
    mx = fmaxf(mx, __shfl_xor(mx, 4));
    float e = __expf(s - mx);
    float sum = e;
    sum += __shfl_xor(sum, 1);
    sum += __shfl_xor(sum, 2);
    sum += __shfl_xor(sum, 4);
    const float p = e / sum;
    probs[(size_t)pair * 64 + lane] = p;
    Ps[wave][lane] = p;  // wave-private, lockstep: no barrier
    float vcf[8];
#pragma unroll
    for (int k2 = 0; k2 < 8; ++k2)
      vcf[k2] = b2f(Vs[wave][k2 * 64 + lane]);
#pragma unroll
    for (int q2 = 0; q2 < 8; ++q2) {
      float4 p0 = *(const float4*)&Ps[wave][q2 * 8];
      float4 p1 = *(const float4*)&Ps[wave][q2 * 8 + 4];
      float acc = p0.x * vcf[0] + p0.y * vcf[1] + p0.z * vcf[2] + p0.w * vcf[3] +
                  p1.x * vcf[4] + p1.y * vcf[5] + p1.z * vcf[6] + p1.w * vcf[7];
      o[(size_t)b * 4096 + q2 * 512 + h * 64 + lane] = f2b(acc);
    }
  }
}

extern "C" void kernel_launch(void* const* d_in, const int* in_sizes, int n_in,
                              void* d_out, int out_size, void* d_ws, size_t ws_size,
                              hipStream_t stream) {
  const float* q = (const float*)d_in[0];
  const float* k = (const float*)d_in[1];
  const float* v = (const float*)d_in[2];
  const float* w_q = (const float*)d_in[3];
  const float* b_q = (const float*)d_in[4];
  const float* w_k = (const float*)d_in[5];
  const float* b_k = (const float*)d_in[6];
  const float* w_v = (const float*)d_in[7];
  const float* b_v = (const float*)d_in[8];
  const float* w_fc = (const float*)d_in[9];
  const float* b_fc = (const float*)d_in[10];

  const int B = in_sizes[0] / 1024;  // 8192
  float* out = (float*)d_out;                   // B*1024 fp32
  float* probs = out + (size_t)B * 1024;        // B*512 fp32 (attn)

  u16* Wq = (u16*)d_ws;
  u16* Wk = Wq + (size_t)4096 * 1024;
  u16* Wv = Wk + (size_t)4096 * 1024;
  u16* Wfc = Wv + (size_t)4096 * 1024;  // 1024x4096
  u16* qb = Wfc + (size_t)4096 * 1024;  // B x 1024 bf16 inputs
  u16* kb = qb + (size_t)B * 1024;
  u16* vb = kb + (size_t)B * 1024;
  u16* scratch = vb + (size_t)B * 1024;
  const size_t fixed_bytes =
      ((size_t)4 * 4096 * 1024 + (size_t)3 * B * 1024) * sizeof(u16);

  // per-row scratch: qp,kp,vp,ao0 (4096 each), bf16
  const size_t per_row = (size_t)(4 * 4096) * sizeof(u16);
  int chunkB = 256;
  for (int c = B; c >= 256; c >>= 1) {
    if (fixed_bytes + (size_t)c * per_row <= ws_size) { chunkB = c; break; }
  }

  u16* qp = scratch;
  u16* kp = qp + (size_t)chunkB * 4096;
  u16* vp = kp + (size_t)chunkB * 4096;
  u16* ao0 = vp + (size_t)chunkB * 4096;  // chunk0 attn out (dedicated)

  // expand circulant weights + convert q/k/v to bf16, once per call
  const int cblocks = B / 2;
  expand_all<<<8192 + 3 * cblocks, 256, 0, stream>>>(
      w_q, w_k, w_v, w_fc, q, k, v, Wq, Wk, Wv, Wfc, qb, kb, vb, cblocks);

  const bool two_chunks = (chunkB * 2 == B);
  for (int cs = 0; cs < B; cs += chunkB) {
    const int nb_p = (chunkB / 256) * (4096 / 256);
    gemm_qkv8p<<<dim3(nb_p, 3), 512, 0, stream>>>(
        qb + (size_t)cs * 1024, kb + (size_t)cs * 1024, vb + (size_t)cs * 1024,
        Wq, Wk, Wv, b_q, b_k, b_v, qp, kp, vp, chunkB, 4096, 1024);
    const int ablocks = (chunkB >= 1024) ? 2048 : chunkB * 2;
    const int aiters = (chunkB * 8) / (ablocks * 4);
    // chunk0 -> dedicated ao0; chunk1 -> alias onto vp (pair-disjoint, safe)
    u16* aoc = (cs == 0) ? ao0 : vp;
    attn_kernel<<<ablocks, 256, 0, stream>>>(qp, kp, vp,
                                             probs + (size_t)cs * 512, aoc,
                                             aiters);
    if (!two_chunks) {
      const int nb_fc = (chunkB / 128) * (1024 / 128);
      gemm_fc2<<<nb_fc, 256, 0, stream>>>(aoc, aoc, Wfc, b_fc,
                                          q + (size_t)cs * 1024,
                                          out + (size_t)cs * 1024, chunkB, 1024,
                                          4096, chunkB);
    }
  }
  if (two_chunks) {
    // single fc braid over both halves: M=8192 -> 256 blocks = 1/CU
    const int nb_fc = (B / 256) * (1024 / 128);
    gemm_fc8p<<<nb_fc, 512, 0, stream>>>(ao0, vp, Wfc, b_fc, q, out, B, 1024,
                                         4096, chunkB);
  }
}